// Round 2
// baseline (354.464 us; speedup 1.0000x reference)
//
#include <hip/hip_runtime.h>
#include <hip/hip_bf16.h>
#include <math.h>

#define TSEQ 2048
#define NHQ 32
#define NHK 8
#define DH 128

typedef __attribute__((ext_vector_type(8))) short short8;
typedef __attribute__((ext_vector_type(4))) float f32x4;
typedef __attribute__((ext_vector_type(4))) short s16x4;

__device__ __forceinline__ short f2bf(float f) {
  union { float f; unsigned u; } v; v.f = f;
  unsigned r = v.u + 0x7fffu + ((v.u >> 16) & 1u);
  return (short)(r >> 16);
}

__device__ __forceinline__ f32x4 zero4() {
  f32x4 z; z[0] = 0.f; z[1] = 0.f; z[2] = 0.f; z[3] = 0.f; return z;
}

// ------------------------------------------------------------------
// prep: q/k/v fp32 -> bf16 (contiguous qkv buffer) + RoPE cos/sin tables
// ------------------------------------------------------------------
__global__ __launch_bounds__(256) void prep_kernel(
    const float* __restrict__ q, const float* __restrict__ k,
    const float* __restrict__ v, short* __restrict__ qkv,
    float* __restrict__ cosT, float* __restrict__ sinT) {
  int gid = blockIdx.x * 256 + threadIdx.x;
  if (gid < 393216) {
    int i4 = gid * 4;
    const float* src = (i4 < 524288) ? (q + i4)
                     : (i4 < 1048576 ? (k + i4 - 524288) : (v + i4 - 1048576));
    float f0 = src[0], f1 = src[1], f2 = src[2], f3 = src[3];
    s16x4 o; o[0] = f2bf(f0); o[1] = f2bf(f1); o[2] = f2bf(f2); o[3] = f2bf(f3);
    *(s16x4*)&qkv[i4] = o;
  } else if (gid < 458752) {
    int idx = (gid - 393216) * 4;
    int t = idx >> 7, d0 = idx & 127;
    float pos = (float)(8192 - TSEQ + t);
#pragma unroll
    for (int jj = 0; jj < 4; ++jj) {
      int d = d0 + jj;
      float inv = powf(10000.0f, -(float)d * (1.0f / 128.0f));
      float f = pos * inv;
      cosT[t * 128 + d] = cosf(f);
      sinT[t * 128 + d] = sinf(f);
    }
  }
}

// ------------------------------------------------------------------
// transpose: W fp32 [K][N] -> bf16 [N][K] via 64x64 LDS tiles
// ------------------------------------------------------------------
__global__ __launch_bounds__(256) void transpose_kernel(
    const float* __restrict__ Wq, const float* __restrict__ Wk,
    const float* __restrict__ Wv, const float* __restrict__ Wo,
    short* __restrict__ WqT, short* __restrict__ WkT,
    short* __restrict__ WvT, short* __restrict__ WoT) {
  __shared__ short tl[64][65];
  int b = blockIdx.x, tid = threadIdx.x;
  const float* S; short* D; int K, N, tr, tc;
  if (b < 256)      { S = Wq; D = WqT; K = 256;  N = 4096; tr = b >> 6;        tc = b & 63; }
  else if (b < 320) { S = Wk; D = WkT; K = 256;  N = 1024; int t = b - 256; tr = t >> 4; tc = t & 15; }
  else if (b < 384) { S = Wv; D = WvT; K = 256;  N = 1024; int t = b - 320; tr = t >> 4; tc = t & 15; }
  else              { S = Wo; D = WoT; K = 4096; N = 256;  int t = b - 384; tr = t >> 2; tc = t & 3; }
  int k0 = tr * 64, n0 = tc * 64;
#pragma unroll
  for (int it = 0; it < 4; ++it) {
    int r = it * 16 + (tid >> 4), c = (tid & 15) * 4;
    const float* s = &S[(size_t)(k0 + r) * N + n0 + c];
    tl[r][c + 0] = f2bf(s[0]); tl[r][c + 1] = f2bf(s[1]);
    tl[r][c + 2] = f2bf(s[2]); tl[r][c + 3] = f2bf(s[3]);
  }
  __syncthreads();
#pragma unroll
  for (int it = 0; it < 4; ++it) {
    int rr = it * 16 + (tid >> 4), cc = (tid & 15) * 4;
    s16x4 o;
    o[0] = tl[cc + 0][rr]; o[1] = tl[cc + 1][rr];
    o[2] = tl[cc + 2][rr]; o[3] = tl[cc + 3][rr];
    *(s16x4*)&D[(size_t)(n0 + rr) * K + k0 + cc] = o;
  }
}

// ------------------------------------------------------------------
// proj: X[2048,256] @ W[256,128] per head, RoPE epilogue, bf16 out.
// Q: [h][t][d]; K: [hk][t][d]; V stored transposed: [hk][d][t].
// Block = 64 rows x 128 cols (one head), 4 waves x 16 rows each.
// ------------------------------------------------------------------
__global__ __launch_bounds__(256) void proj_kernel(
    const short* __restrict__ qkv,
    const short* __restrict__ WqT, const short* __restrict__ WkT,
    const short* __restrict__ WvT,
    const float* __restrict__ cosT, const float* __restrict__ sinT,
    short* __restrict__ Qr, short* __restrict__ Kr, short* __restrict__ Vt) {
  __shared__ short As[64 * 64];
  __shared__ short Bs[128 * 64];
  int tid = threadIdx.x, lane = tid & 63, w = tid >> 6;
  int i = lane & 15, grp = lane >> 4;
  int bh = blockIdx.y, r0 = blockIdx.x * 64;
  const short* X; const short* Wt; short* dst; int vmode = 0;
  if (bh < 32)      { X = qkv;                Wt = WqT + bh * (128 * 256);        dst = Qr + (size_t)bh * TSEQ * DH; }
  else if (bh < 40) { X = qkv + TSEQ * 256;   Wt = WkT + (bh - 32) * (128 * 256); dst = Kr + (size_t)(bh - 32) * TSEQ * DH; }
  else              { X = qkv + 2 * TSEQ * 256; Wt = WvT + (bh - 40) * (128 * 256); dst = Vt + (size_t)(bh - 40) * DH * TSEQ; vmode = 1; }

  f32x4 acc[8];
#pragma unroll
  for (int n = 0; n < 8; ++n) acc[n] = zero4();

  for (int kc = 0; kc < 4; ++kc) {
    __syncthreads();
    { // stage A: 64 rows x 64 k (swizzled 16B chunks)
      int row = tid >> 2, p = tid & 3;
      const short* src = X + (size_t)(r0 + row) * 256 + kc * 64 + p * 16;
      short8 d0 = *(const short8*)(src);
      short8 d1 = *(const short8*)(src + 8);
      int c0 = p * 2;
      *(short8*)&As[row * 64 + ((c0 ^ (row & 7)) * 8)] = d0;
      *(short8*)&As[row * 64 + (((c0 + 1) ^ (row & 7)) * 8)] = d1;
    }
    { // stage B: 128 cols x 64 k from transposed weights
      int row = tid >> 1, p = tid & 1;
      const short* src = Wt + (size_t)row * 256 + kc * 64 + p * 32;
#pragma unroll
      for (int jj = 0; jj < 4; ++jj) {
        short8 dv = *(const short8*)(src + jj * 8);
        int c0 = p * 4 + jj;
        *(short8*)&Bs[row * 64 + ((c0 ^ (row & 7)) * 8)] = dv;
      }
    }
    __syncthreads();
#pragma unroll
    for (int kc2 = 0; kc2 < 2; ++kc2) {
      short8 a = *(const short8*)&As[(w * 16 + i) * 64 + (((kc2 * 4 + grp) ^ (i & 7)) * 8)];
#pragma unroll
      for (int n = 0; n < 8; ++n) {
        short8 bf = *(const short8*)&Bs[(n * 16 + i) * 64 + (((kc2 * 4 + grp) ^ (i & 7)) * 8)];
        acc[n] = __builtin_amdgcn_mfma_f32_16x16x32_bf16(a, bf, acc[n], 0, 0, 0);
      }
    }
  }
  // epilogue: RoPE (partner fragment = n^4, same lane/reg) + bf16 store
#pragma unroll
  for (int r = 0; r < 4; ++r) {
    int t = r0 + w * 16 + grp * 4 + r;
    const float* cr = cosT + (size_t)t * 128;
    const float* sr = sinT + (size_t)t * 128;
#pragma unroll
    for (int n = 0; n < 8; ++n) {
      int d = n * 16 + i;
      float x = acc[n][r];
      float xp = acc[n ^ 4][r];
      float rot = (n < 4) ? -xp : xp;
      float val = x * cr[d] + rot * sr[d];
      short bv = f2bf(val);
      if (vmode) dst[(size_t)d * TSEQ + t] = bv;
      else       dst[(size_t)t * DH + d] = bv;
    }
  }
}

// ------------------------------------------------------------------
// attn: causal flash attention, GQA (4 q-heads per kv-head).
// Block: head h, 64 q-rows; 4 waves x 16 rows. KV tiles of 64 in LDS.
// ------------------------------------------------------------------
#define SCALE 0.08838834764831845f

__global__ __launch_bounds__(256) void attn_kernel(
    const short* __restrict__ Qr, const short* __restrict__ Kr,
    const short* __restrict__ Vt, short* __restrict__ Oa) {
  __shared__ short Ks[64 * 128];   // [kv][dh], chunk-swizzled
  __shared__ short Vs[128 * 64];   // [dh][kv], chunk-swizzled
  __shared__ short Ps[4][16 * 72]; // per-wave P [q][kv]
  int tid = threadIdx.x, lane = tid & 63, w = tid >> 6;
  int i = lane & 15, grp = lane >> 4;
  int h = blockIdx.y, hk = h >> 2;
  int qt = gridDim.x - 1 - blockIdx.x;  // heavy tiles first
  int q0 = qt * 64;
  const short* Qh = Qr + (size_t)h * TSEQ * DH;
  const short* Kh = Kr + (size_t)hk * TSEQ * DH;
  const short* Vh = Vt + (size_t)hk * DH * TSEQ;

  int qrow = q0 + w * 16 + i;
  short8 qf[4];
#pragma unroll
  for (int c = 0; c < 4; ++c)
    qf[c] = *(const short8*)&Qh[(size_t)qrow * DH + c * 32 + grp * 8];

  f32x4 oacc[8];
#pragma unroll
  for (int n = 0; n < 8; ++n) oacc[n] = zero4();
  float mrow[4], lsum[4];
#pragma unroll
  for (int r = 0; r < 4; ++r) { mrow[r] = -3.0e38f; lsum[r] = 0.0f; }

  int ntiles = qt + 1;
  for (int kt = 0; kt < ntiles; ++kt) {
    int kv0 = kt * 64;
    __syncthreads();
    { // stage K tile [64 kv][128 dh]
      int row = tid >> 2, p = tid & 3;
      const short* src = Kh + (size_t)(kv0 + row) * DH + p * 32;
#pragma unroll
      for (int jj = 0; jj < 4; ++jj) {
        short8 dv = *(const short8*)(src + jj * 8);
        int c0 = p * 4 + jj;
        *(short8*)&Ks[row * 128 + ((c0 ^ (row & 15)) * 8)] = dv;
      }
    }
    { // stage V^T tile [128 dh][64 kv]
      int row = tid >> 1, p = tid & 1;
      const short* src = Vh + (size_t)row * TSEQ + kv0 + p * 32;
#pragma unroll
      for (int jj = 0; jj < 4; ++jj) {
        short8 dv = *(const short8*)(src + jj * 8);
        int c0 = p * 4 + jj;
        *(short8*)&Vs[row * 64 + ((c0 ^ (row & 7)) * 8)] = dv;
      }
    }
    __syncthreads();
    // S = Q K^T  (rows: q = grp*4+r, cols: kv = n*16+i)
    f32x4 sacc[4];
#pragma unroll
    for (int n = 0; n < 4; ++n) sacc[n] = zero4();
#pragma unroll
    for (int c = 0; c < 4; ++c) {
#pragma unroll
      for (int n = 0; n < 4; ++n) {
        short8 kb = *(const short8*)&Ks[(n * 16 + i) * 128 + (((c * 4 + grp) ^ i) * 8)];
        sacc[n] = __builtin_amdgcn_mfma_f32_16x16x32_bf16(qf[c], kb, sacc[n], 0, 0, 0);
      }
    }
    bool diag = (kt == ntiles - 1);
    float p_[4][4];
#pragma unroll
    for (int n = 0; n < 4; ++n)
#pragma unroll
      for (int r = 0; r < 4; ++r) {
        float s = sacc[n][r] * SCALE;
        if (diag) {
          int qq = q0 + w * 16 + grp * 4 + r;
          int kk = kv0 + n * 16 + i;
          if (kk > qq) s = -3.0e38f;
        }
        p_[n][r] = s;
      }
    // row max over 4 frags + 16 lanes of the group
    float mnew[4];
#pragma unroll
    for (int r = 0; r < 4; ++r)
      mnew[r] = fmaxf(fmaxf(p_[0][r], p_[1][r]), fmaxf(p_[2][r], p_[3][r]));
#pragma unroll
    for (int off = 1; off <= 8; off <<= 1)
#pragma unroll
      for (int r = 0; r < 4; ++r)
        mnew[r] = fmaxf(mnew[r], __shfl_xor(mnew[r], off));
    float sf[4];
#pragma unroll
    for (int r = 0; r < 4; ++r) {
      float mn = fmaxf(mrow[r], mnew[r]);
      sf[r] = __expf(mrow[r] - mn);
      mrow[r] = mn;
      lsum[r] *= sf[r];
    }
    // P = exp(s - m) -> LDS (reshape to A-fragment layout)
#pragma unroll
    for (int n = 0; n < 4; ++n)
#pragma unroll
      for (int r = 0; r < 4; ++r) {
        float p = __expf(p_[n][r] - mrow[r]);
        lsum[r] += p;
        Ps[w][(grp * 4 + r) * 72 + n * 16 + i] = f2bf(p);
      }
#pragma unroll
    for (int n = 0; n < 8; ++n)
#pragma unroll
      for (int r = 0; r < 4; ++r) oacc[n][r] *= sf[r];
    // O += P V
#pragma unroll
    for (int kc = 0; kc < 2; ++kc) {
      short8 pa = *(const short8*)&Ps[w][i * 72 + kc * 32 + grp * 8];
#pragma unroll
      for (int n = 0; n < 8; ++n) {
        short8 vb = *(const short8*)&Vs[(n * 16 + i) * 64 + (((kc * 4 + grp) ^ (i & 7)) * 8)];
        oacc[n] = __builtin_amdgcn_mfma_f32_16x16x32_bf16(pa, vb, oacc[n], 0, 0, 0);
      }
    }
  }
  // finalize: reduce lsum across the 16-lane group, normalize, store
#pragma unroll
  for (int off = 1; off <= 8; off <<= 1)
#pragma unroll
    for (int r = 0; r < 4; ++r) lsum[r] += __shfl_xor(lsum[r], off);
#pragma unroll
  for (int r = 0; r < 4; ++r) {
    int t = q0 + w * 16 + grp * 4 + r;
    float inv = 1.0f / lsum[r];
#pragma unroll
    for (int n = 0; n < 8; ++n) {
      int d = n * 16 + i;
      Oa[(size_t)t * 4096 + h * 128 + d] = f2bf(oacc[n][r] * inv);
    }
  }
}

// ------------------------------------------------------------------
// outproj: Oa[2048,4096] @ Wo[4096,256] -> fp32 out. 32x64 tiles, 2 waves.
// ------------------------------------------------------------------
__global__ __launch_bounds__(128) void outproj_kernel(
    const short* __restrict__ Oa, const short* __restrict__ WoT,
    float* __restrict__ out) {
  __shared__ short As[32 * 64];
  __shared__ short Bs[64 * 64];
  int tid = threadIdx.x, lane = tid & 63, w = tid >> 6;
  int i = lane & 15, grp = lane >> 4;
  int m0 = blockIdx.x * 32, n0 = blockIdx.y * 64;
  f32x4 acc[4];
#pragma unroll
  for (int n = 0; n < 4; ++n) acc[n] = zero4();
  for (int kc = 0; kc < 64; ++kc) {
    __syncthreads();
    {
      int row = tid >> 2, p = tid & 3;
      const short* src = Oa + (size_t)(m0 + row) * 4096 + kc * 64 + p * 16;
      short8 d0 = *(const short8*)src;
      short8 d1 = *(const short8*)(src + 8);
      int c0 = p * 2;
      *(short8*)&As[row * 64 + ((c0 ^ (row & 7)) * 8)] = d0;
      *(short8*)&As[row * 64 + (((c0 + 1) ^ (row & 7)) * 8)] = d1;
    }
    {
      int row = tid >> 1, p = tid & 1;
      const short* src = WoT + (size_t)(n0 + row) * 4096 + kc * 64 + p * 32;
#pragma unroll
      for (int jj = 0; jj < 4; ++jj) {
        short8 dv = *(const short8*)(src + jj * 8);
        int c0 = p * 4 + jj;
        *(short8*)&Bs[row * 64 + ((c0 ^ (row & 7)) * 8)] = dv;
      }
    }
    __syncthreads();
#pragma unroll
    for (int kc2 = 0; kc2 < 2; ++kc2) {
      short8 a = *(const short8*)&As[(w * 16 + i) * 64 + (((kc2 * 4 + grp) ^ (i & 7)) * 8)];
#pragma unroll
      for (int n = 0; n < 4; ++n) {
        short8 b = *(const short8*)&Bs[(n * 16 + i) * 64 + (((kc2 * 4 + grp) ^ (i & 7)) * 8)];
        acc[n] = __builtin_amdgcn_mfma_f32_16x16x32_bf16(a, b, acc[n], 0, 0, 0);
      }
    }
  }
#pragma unroll
  for (int r = 0; r < 4; ++r) {
    int t = m0 + w * 16 + grp * 4 + r;
#pragma unroll
    for (int n = 0; n < 4; ++n)
      out[(size_t)t * 256 + n0 + n * 16 + i] = acc[n][r];
  }
}

// ------------------------------------------------------------------
extern "C" void kernel_launch(void* const* d_in, const int* in_sizes, int n_in,
                              void* d_out, int out_size, void* d_ws, size_t ws_size,
                              hipStream_t stream) {
  const float* q  = (const float*)d_in[0];
  const float* k  = (const float*)d_in[1];
  const float* v  = (const float*)d_in[2];
  // d_in[3] = causal mask (always tril) -- applied analytically
  const float* Wq = (const float*)d_in[4];
  const float* Wk = (const float*)d_in[5];
  const float* Wv = (const float*)d_in[6];
  const float* Wo = (const float*)d_in[7];
  float* out = (float*)d_out;

  char* p = (char*)d_ws;
  auto take = [&](size_t nbytes) {
    char* r = p; p += (nbytes + 255) & ~(size_t)255; return r;
  };
  short* qkv  = (short*)take(3ull * TSEQ * 256 * 2);
  short* WqT  = (short*)take(4096ull * 256 * 2);
  short* WkT  = (short*)take(1024ull * 256 * 2);
  short* WvT  = (short*)take(1024ull * 256 * 2);
  short* WoT  = (short*)take(256ull * 4096 * 2);
  float* cosT = (float*)take((size_t)TSEQ * 128 * 4);
  float* sinT = (float*)take((size_t)TSEQ * 128 * 4);
  short* Qr   = (short*)take((size_t)NHQ * TSEQ * DH * 2);
  short* Kr   = (short*)take((size_t)NHK * TSEQ * DH * 2);
  short* Vt   = (short*)take((size_t)NHK * TSEQ * DH * 2);
  short* Oa   = (short*)take((size_t)TSEQ * 4096 * 2);

  hipLaunchKernelGGL(prep_kernel, dim3(1792), dim3(256), 0, stream,
                     q, k, v, qkv, cosT, sinT);
  hipLaunchKernelGGL(transpose_kernel, dim3(640), dim3(256), 0, stream,
                     Wq, Wk, Wv, Wo, WqT, WkT, WvT, WoT);
  hipLaunchKernelGGL(proj_kernel, dim3(32, 48), dim3(256), 0, stream,
                     qkv, WqT, WkT, WvT, cosT, sinT, Qr, Kr, Vt);
  hipLaunchKernelGGL(attn_kernel, dim3(32, 32), dim3(256), 0, stream,
                     Qr, Kr, Vt, Oa);
  hipLaunchKernelGGL(outproj_kernel, dim3(64, 4), dim3(128), 0, stream,
                     Oa, WoT, out);
}

// Round 3
// 257.337 us; speedup vs baseline: 1.3774x; 1.3774x over previous
//
#include <hip/hip_runtime.h>
#include <hip/hip_bf16.h>
#include <math.h>

#define TSEQ 2048
#define NHQ 32
#define NHK 8
#define DH 128

typedef __attribute__((ext_vector_type(8))) short short8;
typedef __attribute__((ext_vector_type(4))) float f32x4;
typedef __attribute__((ext_vector_type(4))) short s16x4;

__device__ __forceinline__ short f2bf(float f) {
  union { float f; unsigned u; } v; v.f = f;
  unsigned r = v.u + 0x7fffu + ((v.u >> 16) & 1u);
  return (short)(r >> 16);
}

__device__ __forceinline__ f32x4 zero4() {
  f32x4 z; z[0] = 0.f; z[1] = 0.f; z[2] = 0.f; z[3] = 0.f; return z;
}

// ------------------------------------------------------------------
// prep: q/k/v fp32 -> bf16 (contiguous qkv buffer) + RoPE cos/sin tables
// ------------------------------------------------------------------
__global__ __launch_bounds__(256) void prep_kernel(
    const float* __restrict__ q, const float* __restrict__ k,
    const float* __restrict__ v, short* __restrict__ qkv,
    float* __restrict__ cosT, float* __restrict__ sinT) {
  int gid = blockIdx.x * 256 + threadIdx.x;
  if (gid < 393216) {
    int i4 = gid * 4;
    const float* src = (i4 < 524288) ? (q + i4)
                     : (i4 < 1048576 ? (k + i4 - 524288) : (v + i4 - 1048576));
    float f0 = src[0], f1 = src[1], f2 = src[2], f3 = src[3];
    s16x4 o; o[0] = f2bf(f0); o[1] = f2bf(f1); o[2] = f2bf(f2); o[3] = f2bf(f3);
    *(s16x4*)&qkv[i4] = o;
  } else if (gid < 458752) {
    int idx = (gid - 393216) * 4;
    int t = idx >> 7, d0 = idx & 127;
    float pos = (float)(8192 - TSEQ + t);
#pragma unroll
    for (int jj = 0; jj < 4; ++jj) {
      int d = d0 + jj;
      // 10000^(-d/128) == exp2(-log2(10000)/128 * d)
      float inv = exp2f(-0.10381025296522977f * (float)d);
      float f = pos * inv;
      cosT[t * 128 + d] = cosf(f);
      sinT[t * 128 + d] = sinf(f);
    }
  }
}

// ------------------------------------------------------------------
// transpose: W fp32 [K][N] -> bf16 [N][K] via 64x64 LDS tiles
// ------------------------------------------------------------------
__global__ __launch_bounds__(256) void transpose_kernel(
    const float* __restrict__ Wq, const float* __restrict__ Wk,
    const float* __restrict__ Wv, const float* __restrict__ Wo,
    short* __restrict__ WqT, short* __restrict__ WkT,
    short* __restrict__ WvT, short* __restrict__ WoT) {
  __shared__ short tl[64][65];
  int b = blockIdx.x, tid = threadIdx.x;
  const float* S; short* D; int K, N, tr, tc;
  if (b < 256)      { S = Wq; D = WqT; K = 256;  N = 4096; tr = b >> 6;        tc = b & 63; }
  else if (b < 320) { S = Wk; D = WkT; K = 256;  N = 1024; int t = b - 256; tr = t >> 4; tc = t & 15; }
  else if (b < 384) { S = Wv; D = WvT; K = 256;  N = 1024; int t = b - 320; tr = t >> 4; tc = t & 15; }
  else              { S = Wo; D = WoT; K = 4096; N = 256;  int t = b - 384; tr = t >> 2; tc = t & 3; }
  int k0 = tr * 64, n0 = tc * 64;
#pragma unroll
  for (int it = 0; it < 4; ++it) {
    int r = it * 16 + (tid >> 4), c = (tid & 15) * 4;
    const float* s = &S[(size_t)(k0 + r) * N + n0 + c];
    tl[r][c + 0] = f2bf(s[0]); tl[r][c + 1] = f2bf(s[1]);
    tl[r][c + 2] = f2bf(s[2]); tl[r][c + 3] = f2bf(s[3]);
  }
  __syncthreads();
#pragma unroll
  for (int it = 0; it < 4; ++it) {
    int rr = it * 16 + (tid >> 4), cc = (tid & 15) * 4;
    s16x4 o;
    o[0] = tl[cc + 0][rr]; o[1] = tl[cc + 1][rr];
    o[2] = tl[cc + 2][rr]; o[3] = tl[cc + 3][rr];
    *(s16x4*)&D[(size_t)(n0 + rr) * K + k0 + cc] = o;
  }
}

// ------------------------------------------------------------------
// proj: X[2048,256] @ W[256,128] per head, RoPE epilogue, bf16 out.
// Q: [h][t][d]; K: [hk][t][d]; V stored transposed: [hk][d][t].
// Block = 64 rows x 128 cols (one head), 4 waves x 16 rows each.
// ------------------------------------------------------------------
__global__ __launch_bounds__(256) void proj_kernel(
    const short* __restrict__ qkv,
    const short* __restrict__ WqT, const short* __restrict__ WkT,
    const short* __restrict__ WvT,
    const float* __restrict__ cosT, const float* __restrict__ sinT,
    short* __restrict__ Qr, short* __restrict__ Kr, short* __restrict__ Vt) {
  __shared__ short As[64 * 64];
  __shared__ short Bs[128 * 64];
  int tid = threadIdx.x, lane = tid & 63, w = tid >> 6;
  int i = lane & 15, grp = lane >> 4;
  int bh = blockIdx.y, r0 = blockIdx.x * 64;
  const short* X; const short* Wt; short* dst; int vmode = 0;
  if (bh < 32)      { X = qkv;                Wt = WqT + bh * (128 * 256);        dst = Qr + (size_t)bh * TSEQ * DH; }
  else if (bh < 40) { X = qkv + TSEQ * 256;   Wt = WkT + (bh - 32) * (128 * 256); dst = Kr + (size_t)(bh - 32) * TSEQ * DH; }
  else              { X = qkv + 2 * TSEQ * 256; Wt = WvT + (bh - 40) * (128 * 256); dst = Vt + (size_t)(bh - 40) * DH * TSEQ; vmode = 1; }

  f32x4 acc[8];
#pragma unroll
  for (int n = 0; n < 8; ++n) acc[n] = zero4();

  for (int kc = 0; kc < 4; ++kc) {
    __syncthreads();
    { // stage A: 64 rows x 64 k (swizzled 16B chunks)
      int row = tid >> 2, p = tid & 3;
      const short* src = X + (size_t)(r0 + row) * 256 + kc * 64 + p * 16;
      short8 d0 = *(const short8*)(src);
      short8 d1 = *(const short8*)(src + 8);
      int c0 = p * 2;
      *(short8*)&As[row * 64 + ((c0 ^ (row & 7)) * 8)] = d0;
      *(short8*)&As[row * 64 + (((c0 + 1) ^ (row & 7)) * 8)] = d1;
    }
    { // stage B: 128 cols x 64 k from transposed weights
      int row = tid >> 1, p = tid & 1;
      const short* src = Wt + (size_t)row * 256 + kc * 64 + p * 32;
#pragma unroll
      for (int jj = 0; jj < 4; ++jj) {
        short8 dv = *(const short8*)(src + jj * 8);
        int c0 = p * 4 + jj;
        *(short8*)&Bs[row * 64 + ((c0 ^ (row & 7)) * 8)] = dv;
      }
    }
    __syncthreads();
#pragma unroll
    for (int kc2 = 0; kc2 < 2; ++kc2) {
      short8 a = *(const short8*)&As[(w * 16 + i) * 64 + (((kc2 * 4 + grp) ^ (i & 7)) * 8)];
#pragma unroll
      for (int n = 0; n < 8; ++n) {
        short8 bf = *(const short8*)&Bs[(n * 16 + i) * 64 + (((kc2 * 4 + grp) ^ (i & 7)) * 8)];
        acc[n] = __builtin_amdgcn_mfma_f32_16x16x32_bf16(a, bf, acc[n], 0, 0, 0);
      }
    }
  }
  // epilogue: RoPE (partner fragment = n^4, same lane/reg) + bf16 store
#pragma unroll
  for (int r = 0; r < 4; ++r) {
    int t = r0 + w * 16 + grp * 4 + r;
    const float* cr = cosT + (size_t)t * 128;
    const float* sr = sinT + (size_t)t * 128;
#pragma unroll
    for (int n = 0; n < 8; ++n) {
      int d = n * 16 + i;
      float x = acc[n][r];
      float xp = acc[n ^ 4][r];
      float rot = (n < 4) ? -xp : xp;
      float val = x * cr[d] + rot * sr[d];
      short bv = f2bf(val);
      if (vmode) dst[(size_t)d * TSEQ + t] = bv;
      else       dst[(size_t)t * DH + d] = bv;
    }
  }
}

// ------------------------------------------------------------------
// attn: causal flash attention, GQA (4 q-heads per kv-head).
// Load-balanced pairing: block (bx,h) processes q-tiles (31-bx) and bx
// sequentially -> every block does exactly 33 kv-tile iterations.
// 512 blocks = 2 resident/CU (LDS 41KB, cap 3) -> no tail.
// ------------------------------------------------------------------
#define SCALE 0.08838834764831845f

__global__ __launch_bounds__(256) void attn_kernel(
    const short* __restrict__ Qr, const short* __restrict__ Kr,
    const short* __restrict__ Vt, short* __restrict__ Oa) {
  __shared__ short Ks[64 * 128];   // [kv][dh], chunk-swizzled
  __shared__ short Vs[128 * 64];   // [dh][kv], chunk-swizzled
  __shared__ short Ps[4][16 * 72]; // per-wave P [q][kv]
  int tid = threadIdx.x, lane = tid & 63, w = tid >> 6;
  int i = lane & 15, grp = lane >> 4;
  int h = blockIdx.y, hk = h >> 2;
  const short* Qh = Qr + (size_t)h * TSEQ * DH;
  const short* Kh = Kr + (size_t)hk * TSEQ * DH;
  const short* Vh = Vt + (size_t)hk * DH * TSEQ;

  for (int half = 0; half < 2; ++half) {
    int qt = half ? blockIdx.x : (31 - blockIdx.x);  // heavy half first
    int q0 = qt * 64;
    int qrow = q0 + w * 16 + i;
    short8 qf[4];
#pragma unroll
    for (int c = 0; c < 4; ++c)
      qf[c] = *(const short8*)&Qh[(size_t)qrow * DH + c * 32 + grp * 8];

    f32x4 oacc[8];
#pragma unroll
    for (int n = 0; n < 8; ++n) oacc[n] = zero4();
    float mrow[4], lsum[4];
#pragma unroll
    for (int r = 0; r < 4; ++r) { mrow[r] = -3.0e38f; lsum[r] = 0.0f; }

    int ntiles = qt + 1;
    for (int kt = 0; kt < ntiles; ++kt) {
      int kv0 = kt * 64;
      __syncthreads();
      { // stage K tile [64 kv][128 dh]
        int row = tid >> 2, p = tid & 3;
        const short* src = Kh + (size_t)(kv0 + row) * DH + p * 32;
#pragma unroll
        for (int jj = 0; jj < 4; ++jj) {
          short8 dv = *(const short8*)(src + jj * 8);
          int c0 = p * 4 + jj;
          *(short8*)&Ks[row * 128 + ((c0 ^ (row & 15)) * 8)] = dv;
        }
      }
      { // stage V^T tile [128 dh][64 kv]
        int row = tid >> 1, p = tid & 1;
        const short* src = Vh + (size_t)row * TSEQ + kv0 + p * 32;
#pragma unroll
        for (int jj = 0; jj < 4; ++jj) {
          short8 dv = *(const short8*)(src + jj * 8);
          int c0 = p * 4 + jj;
          *(short8*)&Vs[row * 64 + ((c0 ^ (row & 7)) * 8)] = dv;
        }
      }
      __syncthreads();
      // S = Q K^T  (rows: q = grp*4+r, cols: kv = n*16+i)
      f32x4 sacc[4];
#pragma unroll
      for (int n = 0; n < 4; ++n) sacc[n] = zero4();
#pragma unroll
      for (int c = 0; c < 4; ++c) {
#pragma unroll
        for (int n = 0; n < 4; ++n) {
          short8 kb = *(const short8*)&Ks[(n * 16 + i) * 128 + (((c * 4 + grp) ^ i) * 8)];
          sacc[n] = __builtin_amdgcn_mfma_f32_16x16x32_bf16(qf[c], kb, sacc[n], 0, 0, 0);
        }
      }
      bool diag = (kt == ntiles - 1);
      float p_[4][4];
#pragma unroll
      for (int n = 0; n < 4; ++n)
#pragma unroll
        for (int r = 0; r < 4; ++r) {
          float s = sacc[n][r] * SCALE;
          if (diag) {
            int qq = q0 + w * 16 + grp * 4 + r;
            int kk = kv0 + n * 16 + i;
            if (kk > qq) s = -3.0e38f;
          }
          p_[n][r] = s;
        }
      // row max over 4 frags + 16 lanes of the group
      float mnew[4];
#pragma unroll
      for (int r = 0; r < 4; ++r)
        mnew[r] = fmaxf(fmaxf(p_[0][r], p_[1][r]), fmaxf(p_[2][r], p_[3][r]));
#pragma unroll
      for (int off = 1; off <= 8; off <<= 1)
#pragma unroll
        for (int r = 0; r < 4; ++r)
          mnew[r] = fmaxf(mnew[r], __shfl_xor(mnew[r], off));
      float sf[4];
#pragma unroll
      for (int r = 0; r < 4; ++r) {
        float mn = fmaxf(mrow[r], mnew[r]);
        sf[r] = __expf(mrow[r] - mn);
        mrow[r] = mn;
        lsum[r] *= sf[r];
      }
      // P = exp(s - m) -> LDS (reshape to A-fragment layout)
#pragma unroll
      for (int n = 0; n < 4; ++n)
#pragma unroll
        for (int r = 0; r < 4; ++r) {
          float p = __expf(p_[n][r] - mrow[r]);
          lsum[r] += p;
          Ps[w][(grp * 4 + r) * 72 + n * 16 + i] = f2bf(p);
        }
#pragma unroll
      for (int n = 0; n < 8; ++n)
#pragma unroll
        for (int r = 0; r < 4; ++r) oacc[n][r] *= sf[r];
      // O += P V
#pragma unroll
      for (int kc = 0; kc < 2; ++kc) {
        short8 pa = *(const short8*)&Ps[w][i * 72 + kc * 32 + grp * 8];
#pragma unroll
        for (int n = 0; n < 8; ++n) {
          short8 vb = *(const short8*)&Vs[(n * 16 + i) * 64 + (((kc * 4 + grp) ^ (i & 7)) * 8)];
          oacc[n] = __builtin_amdgcn_mfma_f32_16x16x32_bf16(pa, vb, oacc[n], 0, 0, 0);
        }
      }
    }
    // finalize: reduce lsum across the 16-lane group, normalize, store
#pragma unroll
    for (int off = 1; off <= 8; off <<= 1)
#pragma unroll
      for (int r = 0; r < 4; ++r) lsum[r] += __shfl_xor(lsum[r], off);
#pragma unroll
    for (int r = 0; r < 4; ++r) {
      int t = q0 + w * 16 + grp * 4 + r;
      float inv = 1.0f / lsum[r];
#pragma unroll
      for (int n = 0; n < 8; ++n) {
        int d = n * 16 + i;
        Oa[(size_t)t * 4096 + h * 128 + d] = f2bf(oacc[n][r] * inv);
      }
    }
  }
}

// ------------------------------------------------------------------
// outproj: Oa[2048,4096] @ Wo[4096,256], split-K=4 -> fp32 partials.
// Block = 128 rows x 64 cols, 4 waves x (32 rows = 2 m-frags, 4 n-frags).
// Grid (16 m, 4 n, 4 splitK) = 256 equal blocks, 16 K-iters each.
// ------------------------------------------------------------------
__global__ __launch_bounds__(256) void outproj_kernel(
    const short* __restrict__ Oa, const short* __restrict__ WoT,
    float* __restrict__ Opart) {
  __shared__ short As[128 * 64];
  __shared__ short Bs[64 * 64];
  int tid = threadIdx.x, lane = tid & 63, w = tid >> 6;
  int i = lane & 15, grp = lane >> 4;
  int m0 = blockIdx.x * 128, n0 = blockIdx.y * 64, z = blockIdx.z;
  f32x4 acc[2][4];
#pragma unroll
  for (int mf = 0; mf < 2; ++mf)
#pragma unroll
    for (int nf = 0; nf < 4; ++nf) acc[mf][nf] = zero4();
  for (int kc = z * 16; kc < z * 16 + 16; ++kc) {
    __syncthreads();
    { // stage A: 128 rows x 64 k
      int row = tid >> 1, p = tid & 1;
      const short* src = Oa + (size_t)(m0 + row) * 4096 + kc * 64 + p * 32;
#pragma unroll
      for (int jj = 0; jj < 4; ++jj) {
        short8 dv = *(const short8*)(src + jj * 8);
        int c0 = p * 4 + jj;
        *(short8*)&As[row * 64 + ((c0 ^ (row & 7)) * 8)] = dv;
      }
    }
    { // stage B: 64 cols x 64 k
      int row = tid >> 2, p = tid & 3;
      const short* src = WoT + (size_t)(n0 + row) * 4096 + kc * 64 + p * 16;
      short8 d0 = *(const short8*)src;
      short8 d1 = *(const short8*)(src + 8);
      int c0 = p * 2;
      *(short8*)&Bs[row * 64 + ((c0 ^ (row & 7)) * 8)] = d0;
      *(short8*)&Bs[row * 64 + (((c0 + 1) ^ (row & 7)) * 8)] = d1;
    }
    __syncthreads();
#pragma unroll
    for (int kc2 = 0; kc2 < 2; ++kc2) {
#pragma unroll
      for (int mf = 0; mf < 2; ++mf) {
        short8 a = *(const short8*)&As[(w * 32 + mf * 16 + i) * 64 + (((kc2 * 4 + grp) ^ (i & 7)) * 8)];
#pragma unroll
        for (int nf = 0; nf < 4; ++nf) {
          short8 b = *(const short8*)&Bs[(nf * 16 + i) * 64 + (((kc2 * 4 + grp) ^ (i & 7)) * 8)];
          acc[mf][nf] = __builtin_amdgcn_mfma_f32_16x16x32_bf16(a, b, acc[mf][nf], 0, 0, 0);
        }
      }
    }
  }
  float* dst = Opart + (size_t)z * (TSEQ * 256);
#pragma unroll
  for (int mf = 0; mf < 2; ++mf)
#pragma unroll
    for (int r = 0; r < 4; ++r) {
      int t = m0 + w * 32 + mf * 16 + grp * 4 + r;
#pragma unroll
      for (int nf = 0; nf < 4; ++nf)
        dst[(size_t)t * 256 + n0 + nf * 16 + i] = acc[mf][nf][r];
    }
}

// ------------------------------------------------------------------
// reduce: out = sum of 4 split-K partials
// ------------------------------------------------------------------
__global__ __launch_bounds__(256) void reduce_kernel(
    const float* __restrict__ Opart, float* __restrict__ out) {
  int gid = blockIdx.x * 256 + threadIdx.x;
  int i4 = gid * 4;
  f32x4 s = *(const f32x4*)&Opart[i4];
#pragma unroll
  for (int z = 1; z < 4; ++z) {
    f32x4 p = *(const f32x4*)&Opart[(size_t)z * (TSEQ * 256) + i4];
    s[0] += p[0]; s[1] += p[1]; s[2] += p[2]; s[3] += p[3];
  }
  *(f32x4*)&out[i4] = s;
}

// ------------------------------------------------------------------
extern "C" void kernel_launch(void* const* d_in, const int* in_sizes, int n_in,
                              void* d_out, int out_size, void* d_ws, size_t ws_size,
                              hipStream_t stream) {
  const float* q  = (const float*)d_in[0];
  const float* k  = (const float*)d_in[1];
  const float* v  = (const float*)d_in[2];
  // d_in[3] = causal mask (always tril) -- applied analytically
  const float* Wq = (const float*)d_in[4];
  const float* Wk = (const float*)d_in[5];
  const float* Wv = (const float*)d_in[6];
  const float* Wo = (const float*)d_in[7];
  float* out = (float*)d_out;

  char* p = (char*)d_ws;
  auto take = [&](size_t nbytes) {
    char* r = p; p += (nbytes + 255) & ~(size_t)255; return r;
  };
  short* qkv  = (short*)take(3ull * TSEQ * 256 * 2);
  short* WqT  = (short*)take(4096ull * 256 * 2);
  short* WkT  = (short*)take(1024ull * 256 * 2);
  short* WvT  = (short*)take(1024ull * 256 * 2);
  short* WoT  = (short*)take(256ull * 4096 * 2);
  float* cosT = (float*)take((size_t)TSEQ * 128 * 4);
  float* sinT = (float*)take((size_t)TSEQ * 128 * 4);
  short* Qr   = (short*)take((size_t)NHQ * TSEQ * DH * 2);
  short* Kr   = (short*)take((size_t)NHK * TSEQ * DH * 2);
  short* Vt   = (short*)take((size_t)NHK * TSEQ * DH * 2);
  short* Oa   = (short*)take((size_t)TSEQ * 4096 * 2);
  // split-K partials (4 x 2 MB fp32) alias Qr (16 MB): Qr is dead after
  // attn_kernel; outproj/reduce run strictly after it on the same stream.
  float* Opart = (float*)Qr;

  hipLaunchKernelGGL(prep_kernel, dim3(1792), dim3(256), 0, stream,
                     q, k, v, qkv, cosT, sinT);
  hipLaunchKernelGGL(transpose_kernel, dim3(640), dim3(256), 0, stream,
                     Wq, Wk, Wv, Wo, WqT, WkT, WvT, WoT);
  hipLaunchKernelGGL(proj_kernel, dim3(32, 48), dim3(256), 0, stream,
                     qkv, WqT, WkT, WvT, cosT, sinT, Qr, Kr, Vt);
  hipLaunchKernelGGL(attn_kernel, dim3(16, 32), dim3(256), 0, stream,
                     Qr, Kr, Vt, Oa);
  hipLaunchKernelGGL(outproj_kernel, dim3(16, 4, 4), dim3(256), 0, stream,
                     Oa, WoT, Opart);
  hipLaunchKernelGGL(reduce_kernel, dim3(512), dim3(256), 0, stream,
                     Opart, out);
}

// Round 4
// 247.157 us; speedup vs baseline: 1.4342x; 1.0412x over previous
//
#include <hip/hip_runtime.h>
#include <hip/hip_bf16.h>
#include <math.h>

#define TSEQ 2048
#define NHQ 32
#define NHK 8
#define DH 128

typedef __attribute__((ext_vector_type(8))) short short8;
typedef __attribute__((ext_vector_type(4))) float f32x4;
typedef __attribute__((ext_vector_type(4))) short s16x4;

__device__ __forceinline__ short f2bf(float f) {
  union { float f; unsigned u; } v; v.f = f;
  unsigned r = v.u + 0x7fffu + ((v.u >> 16) & 1u);
  return (short)(r >> 16);
}

__device__ __forceinline__ f32x4 zero4() {
  f32x4 z; z[0] = 0.f; z[1] = 0.f; z[2] = 0.f; z[3] = 0.f; return z;
}

// async 16B global->LDS DMA. LDS dest is wave-uniform base + lane*16 (m104);
// per-lane swizzle goes on the GLOBAL source address (m173).
__device__ __forceinline__ void async_cp16(const short* g, short* l) {
  __builtin_amdgcn_global_load_lds(
      (const __attribute__((address_space(1))) unsigned int*)g,
      (__attribute__((address_space(3))) unsigned int*)l, 16, 0, 0);
}

// ------------------------------------------------------------------
// prep+transpose fused (independent work, one dispatch):
//  blocks [0,1792): q/k/v fp32->bf16 + RoPE cos/sin tables
//  blocks [1792,2432): W fp32 [K][N] -> bf16 [N][K] via 64x64 LDS tiles
// ------------------------------------------------------------------
__global__ __launch_bounds__(256) void prep_transpose_kernel(
    const float* __restrict__ q, const float* __restrict__ k,
    const float* __restrict__ v, short* __restrict__ qkv,
    float* __restrict__ cosT, float* __restrict__ sinT,
    const float* __restrict__ Wq, const float* __restrict__ Wk,
    const float* __restrict__ Wv, const float* __restrict__ Wo,
    short* __restrict__ WqT, short* __restrict__ WkT,
    short* __restrict__ WvT, short* __restrict__ WoT) {
  __shared__ short tl[64][65];
  int bx = blockIdx.x, tid = threadIdx.x;
  if (bx < 1792) {
    int gid = bx * 256 + tid;
    if (gid < 393216) {
      int i4 = gid * 4;
      const float* src = (i4 < 524288) ? (q + i4)
                       : (i4 < 1048576 ? (k + i4 - 524288) : (v + i4 - 1048576));
      float f0 = src[0], f1 = src[1], f2 = src[2], f3 = src[3];
      s16x4 o; o[0] = f2bf(f0); o[1] = f2bf(f1); o[2] = f2bf(f2); o[3] = f2bf(f3);
      *(s16x4*)&qkv[i4] = o;
    } else if (gid < 458752) {
      int idx = (gid - 393216) * 4;
      int t = idx >> 7, d0 = idx & 127;
      float pos = (float)(8192 - TSEQ + t);
#pragma unroll
      for (int jj = 0; jj < 4; ++jj) {
        int d = d0 + jj;
        float inv = exp2f(-0.10381025296522977f * (float)d);
        float f = pos * inv;
        cosT[t * 128 + d] = cosf(f);
        sinT[t * 128 + d] = sinf(f);
      }
    }
    return;
  }
  int b = bx - 1792;
  const float* S; short* D; int K, N, tr, tc;
  if (b < 256)      { S = Wq; D = WqT; K = 256;  N = 4096; tr = b >> 6;        tc = b & 63; }
  else if (b < 320) { S = Wk; D = WkT; K = 256;  N = 1024; int t = b - 256; tr = t >> 4; tc = t & 15; }
  else if (b < 384) { S = Wv; D = WvT; K = 256;  N = 1024; int t = b - 320; tr = t >> 4; tc = t & 15; }
  else              { S = Wo; D = WoT; K = 4096; N = 256;  int t = b - 384; tr = t >> 2; tc = t & 3; }
  int k0 = tr * 64, n0 = tc * 64;
#pragma unroll
  for (int it = 0; it < 4; ++it) {
    int r = it * 16 + (tid >> 4), c = (tid & 15) * 4;
    const float* s = &S[(size_t)(k0 + r) * N + n0 + c];
    tl[r][c + 0] = f2bf(s[0]); tl[r][c + 1] = f2bf(s[1]);
    tl[r][c + 2] = f2bf(s[2]); tl[r][c + 3] = f2bf(s[3]);
  }
  __syncthreads();
#pragma unroll
  for (int it = 0; it < 4; ++it) {
    int rr = it * 16 + (tid >> 4), cc = (tid & 15) * 4;
    s16x4 o;
    o[0] = tl[cc + 0][rr]; o[1] = tl[cc + 1][rr];
    o[2] = tl[cc + 2][rr]; o[3] = tl[cc + 3][rr];
    *(s16x4*)&D[(size_t)(n0 + rr) * K + k0 + cc] = o;
  }
}

// ------------------------------------------------------------------
// proj: X[2048,256] @ W[256,128] per head, RoPE epilogue, bf16 out.
// ------------------------------------------------------------------
__global__ __launch_bounds__(256) void proj_kernel(
    const short* __restrict__ qkv,
    const short* __restrict__ WqT, const short* __restrict__ WkT,
    const short* __restrict__ WvT,
    const float* __restrict__ cosT, const float* __restrict__ sinT,
    short* __restrict__ Qr, short* __restrict__ Kr, short* __restrict__ Vt) {
  __shared__ short As[64 * 64];
  __shared__ short Bs[128 * 64];
  int tid = threadIdx.x, lane = tid & 63, w = tid >> 6;
  int i = lane & 15, grp = lane >> 4;
  int bh = blockIdx.y, r0 = blockIdx.x * 64;
  const short* X; const short* Wt; short* dst; int vmode = 0;
  if (bh < 32)      { X = qkv;                Wt = WqT + bh * (128 * 256);        dst = Qr + (size_t)bh * TSEQ * DH; }
  else if (bh < 40) { X = qkv + TSEQ * 256;   Wt = WkT + (bh - 32) * (128 * 256); dst = Kr + (size_t)(bh - 32) * TSEQ * DH; }
  else              { X = qkv + 2 * TSEQ * 256; Wt = WvT + (bh - 40) * (128 * 256); dst = Vt + (size_t)(bh - 40) * DH * TSEQ; vmode = 1; }

  f32x4 acc[8];
#pragma unroll
  for (int n = 0; n < 8; ++n) acc[n] = zero4();

  for (int kc = 0; kc < 4; ++kc) {
    __syncthreads();
    { // stage A: 64 rows x 64 k (swizzled 16B chunks)
      int row = tid >> 2, p = tid & 3;
      const short* src = X + (size_t)(r0 + row) * 256 + kc * 64 + p * 16;
      short8 d0 = *(const short8*)(src);
      short8 d1 = *(const short8*)(src + 8);
      int c0 = p * 2;
      *(short8*)&As[row * 64 + ((c0 ^ (row & 7)) * 8)] = d0;
      *(short8*)&As[row * 64 + (((c0 + 1) ^ (row & 7)) * 8)] = d1;
    }
    { // stage B: 128 cols x 64 k from transposed weights
      int row = tid >> 1, p = tid & 1;
      const short* src = Wt + (size_t)row * 256 + kc * 64 + p * 32;
#pragma unroll
      for (int jj = 0; jj < 4; ++jj) {
        short8 dv = *(const short8*)(src + jj * 8);
        int c0 = p * 4 + jj;
        *(short8*)&Bs[row * 64 + ((c0 ^ (row & 7)) * 8)] = dv;
      }
    }
    __syncthreads();
#pragma unroll
    for (int kc2 = 0; kc2 < 2; ++kc2) {
      short8 a = *(const short8*)&As[(w * 16 + i) * 64 + (((kc2 * 4 + grp) ^ (i & 7)) * 8)];
#pragma unroll
      for (int n = 0; n < 8; ++n) {
        short8 bf = *(const short8*)&Bs[(n * 16 + i) * 64 + (((kc2 * 4 + grp) ^ (i & 7)) * 8)];
        acc[n] = __builtin_amdgcn_mfma_f32_16x16x32_bf16(a, bf, acc[n], 0, 0, 0);
      }
    }
  }
#pragma unroll
  for (int r = 0; r < 4; ++r) {
    int t = r0 + w * 16 + grp * 4 + r;
    const float* cr = cosT + (size_t)t * 128;
    const float* sr = sinT + (size_t)t * 128;
#pragma unroll
    for (int n = 0; n < 8; ++n) {
      int d = n * 16 + i;
      float x = acc[n][r];
      float xp = acc[n ^ 4][r];
      float rot = (n < 4) ? -xp : xp;
      float val = x * cr[d] + rot * sr[d];
      short bv = f2bf(val);
      if (vmode) dst[(size_t)d * TSEQ + t] = bv;
      else       dst[(size_t)t * DH + d] = bv;
    }
  }
}

// ------------------------------------------------------------------
// attn: causal flash attention, GQA. QBLK=128 (8 waves x 16 q-rows),
// KV tiles of 64 DMA-staged via global_load_lds (pre-swizzled source,
// linear LDS dest). Heavy-first grid (16,32). defer-max + setprio.
// ------------------------------------------------------------------
#define SCALE 0.08838834764831845f

__global__ __launch_bounds__(512, 4) void attn_kernel(
    const short* __restrict__ Qr, const short* __restrict__ Kr,
    const short* __restrict__ Vt, short* __restrict__ Oa) {
  __shared__ __attribute__((aligned(16))) short Ks[64 * 128]; // [kv][dh] chunk-swz
  __shared__ __attribute__((aligned(16))) short Vs[128 * 64]; // [dh][kv] chunk-swz
  __shared__ short Ps[8][16 * 72];
  int tid = threadIdx.x, lane = tid & 63, w = tid >> 6;  // w in 0..7
  int i = lane & 15, grp = lane >> 4;
  int h = blockIdx.y, hk = h >> 2;
  int qt = 15 - blockIdx.x;  // heavy tiles first
  int q0 = qt * 128;
  const short* Qh = Qr + (size_t)h * TSEQ * DH;
  const short* Kh = Kr + (size_t)hk * TSEQ * DH;
  const short* Vh = Vt + (size_t)hk * DH * TSEQ;

  int qrow = q0 + w * 16 + i;
  short8 qf[4];
#pragma unroll
  for (int c = 0; c < 4; ++c)
    qf[c] = *(const short8*)&Qh[(size_t)qrow * DH + c * 32 + grp * 8];

  f32x4 oacc[8];
#pragma unroll
  for (int n = 0; n < 8; ++n) oacc[n] = zero4();
  float mrow[4], lsum[4];
#pragma unroll
  for (int r = 0; r < 4; ++r) { mrow[r] = -3.0e38f; lsum[r] = 0.0f; }

  int ntiles = 2 * qt + 2;
  int wave_max_row = q0 + w * 16 + 15;
  for (int kt = 0; kt < ntiles; ++kt) {
    int kv0 = kt * 64;
    __syncthreads();
    { // K tile: 64 rows x 128 shorts = 1024 16B-chunks; wave w -> chunks
      // [hf*512 + w*64 + lane]. LDS linear; src chunk = c ^ (row&15).
#pragma unroll
      for (int hf = 0; hf < 2; ++hf) {
        int ci = hf * 512 + w * 64 + lane;
        int row = ci >> 4, c = ci & 15;
        const short* src = Kh + (size_t)(kv0 + row) * DH + ((c ^ (row & 15)) << 3);
        async_cp16(src, Ks + hf * 4096 + w * 512);
      }
      // V tile: 128 rows x 64 shorts = 1024 chunks; src chunk = c ^ (row&7).
#pragma unroll
      for (int hf = 0; hf < 2; ++hf) {
        int ci = hf * 512 + w * 64 + lane;
        int row = ci >> 3, c = ci & 7;
        const short* src = Vh + (size_t)row * TSEQ + kv0 + ((c ^ (row & 7)) << 3);
        async_cp16(src, Vs + hf * 4096 + w * 512);
      }
    }
    __syncthreads();
    if (kv0 <= wave_max_row) {  // wave-uniform: skip fully-masked tiles
      // S = Q K^T  (rows: q = grp*4+r, cols: kv = n*16+i)
      f32x4 sacc[4];
#pragma unroll
      for (int n = 0; n < 4; ++n) sacc[n] = zero4();
      __builtin_amdgcn_s_setprio(1);
#pragma unroll
      for (int c = 0; c < 4; ++c) {
#pragma unroll
        for (int n = 0; n < 4; ++n) {
          short8 kb = *(const short8*)&Ks[(n * 16 + i) * 128 + (((c * 4 + grp) ^ i) * 8)];
          sacc[n] = __builtin_amdgcn_mfma_f32_16x16x32_bf16(qf[c], kb, sacc[n], 0, 0, 0);
        }
      }
      __builtin_amdgcn_s_setprio(0);
      bool diag = (kt >= ntiles - 2);  // last two tiles cross the diagonal
      float p_[4][4];
#pragma unroll
      for (int n = 0; n < 4; ++n)
#pragma unroll
        for (int r = 0; r < 4; ++r) {
          float s = sacc[n][r] * SCALE;
          if (diag) {
            int qq = q0 + w * 16 + grp * 4 + r;
            int kk = kv0 + n * 16 + i;
            if (kk > qq) s = -3.0e38f;
          }
          p_[n][r] = s;
        }
      float mnew[4];
#pragma unroll
      for (int r = 0; r < 4; ++r)
        mnew[r] = fmaxf(fmaxf(p_[0][r], p_[1][r]), fmaxf(p_[2][r], p_[3][r]));
#pragma unroll
      for (int off = 1; off <= 8; off <<= 1)
#pragma unroll
        for (int r = 0; r < 4; ++r)
          mnew[r] = fmaxf(mnew[r], __shfl_xor(mnew[r], off));
      // defer-max (T13): skip rescale while max growth <= 8
      bool ok = true;
#pragma unroll
      for (int r = 0; r < 4; ++r) ok = ok && (mnew[r] <= mrow[r] + 8.0f);
      if (!__all(ok ? 1 : 0)) {
#pragma unroll
        for (int r = 0; r < 4; ++r) {
          float mn = fmaxf(mrow[r], mnew[r]);
          float sfv = __expf(mrow[r] - mn);
          mrow[r] = mn;
          lsum[r] *= sfv;
#pragma unroll
          for (int n = 0; n < 8; ++n) oacc[n][r] *= sfv;
        }
      }
#pragma unroll
      for (int n = 0; n < 4; ++n)
#pragma unroll
        for (int r = 0; r < 4; ++r) {
          float p = __expf(p_[n][r] - mrow[r]);
          lsum[r] += p;
          Ps[w][(grp * 4 + r) * 72 + n * 16 + i] = f2bf(p);
        }
      // O += P V
      __builtin_amdgcn_s_setprio(1);
#pragma unroll
      for (int kc = 0; kc < 2; ++kc) {
        short8 pa = *(const short8*)&Ps[w][i * 72 + kc * 32 + grp * 8];
#pragma unroll
        for (int n = 0; n < 8; ++n) {
          short8 vb = *(const short8*)&Vs[(n * 16 + i) * 64 + (((kc * 4 + grp) ^ (i & 7)) * 8)];
          oacc[n] = __builtin_amdgcn_mfma_f32_16x16x32_bf16(pa, vb, oacc[n], 0, 0, 0);
        }
      }
      __builtin_amdgcn_s_setprio(0);
    }
  }
#pragma unroll
  for (int off = 1; off <= 8; off <<= 1)
#pragma unroll
    for (int r = 0; r < 4; ++r) lsum[r] += __shfl_xor(lsum[r], off);
#pragma unroll
  for (int r = 0; r < 4; ++r) {
    int t = q0 + w * 16 + grp * 4 + r;
    float inv = 1.0f / lsum[r];
#pragma unroll
    for (int n = 0; n < 8; ++n) {
      int d = n * 16 + i;
      Oa[(size_t)t * 4096 + h * 128 + d] = f2bf(oacc[n][r] * inv);
    }
  }
}

// ------------------------------------------------------------------
// outproj: Oa[2048,4096] @ Wo[4096,256], split-K=4 -> fp32 partials.
// ------------------------------------------------------------------
__global__ __launch_bounds__(256) void outproj_kernel(
    const short* __restrict__ Oa, const short* __restrict__ WoT,
    float* __restrict__ Opart) {
  __shared__ short As[128 * 64];
  __shared__ short Bs[64 * 64];
  int tid = threadIdx.x, lane = tid & 63, w = tid >> 6;
  int i = lane & 15, grp = lane >> 4;
  int m0 = blockIdx.x * 128, n0 = blockIdx.y * 64, z = blockIdx.z;
  f32x4 acc[2][4];
#pragma unroll
  for (int mf = 0; mf < 2; ++mf)
#pragma unroll
    for (int nf = 0; nf < 4; ++nf) acc[mf][nf] = zero4();
  for (int kc = z * 16; kc < z * 16 + 16; ++kc) {
    __syncthreads();
    {
      int row = tid >> 1, p = tid & 1;
      const short* src = Oa + (size_t)(m0 + row) * 4096 + kc * 64 + p * 32;
#pragma unroll
      for (int jj = 0; jj < 4; ++jj) {
        short8 dv = *(const short8*)(src + jj * 8);
        int c0 = p * 4 + jj;
        *(short8*)&As[row * 64 + ((c0 ^ (row & 7)) * 8)] = dv;
      }
    }
    {
      int row = tid >> 2, p = tid & 3;
      const short* src = WoT + (size_t)(n0 + row) * 4096 + kc * 64 + p * 16;
      short8 d0 = *(const short8*)src;
      short8 d1 = *(const short8*)(src + 8);
      int c0 = p * 2;
      *(short8*)&Bs[row * 64 + ((c0 ^ (row & 7)) * 8)] = d0;
      *(short8*)&Bs[row * 64 + (((c0 + 1) ^ (row & 7)) * 8)] = d1;
    }
    __syncthreads();
#pragma unroll
    for (int kc2 = 0; kc2 < 2; ++kc2) {
#pragma unroll
      for (int mf = 0; mf < 2; ++mf) {
        short8 a = *(const short8*)&As[(w * 32 + mf * 16 + i) * 64 + (((kc2 * 4 + grp) ^ (i & 7)) * 8)];
#pragma unroll
        for (int nf = 0; nf < 4; ++nf) {
          short8 b = *(const short8*)&Bs[(nf * 16 + i) * 64 + (((kc2 * 4 + grp) ^ (i & 7)) * 8)];
          acc[mf][nf] = __builtin_amdgcn_mfma_f32_16x16x32_bf16(a, b, acc[mf][nf], 0, 0, 0);
        }
      }
    }
  }
  float* dst = Opart + (size_t)z * (TSEQ * 256);
#pragma unroll
  for (int mf = 0; mf < 2; ++mf)
#pragma unroll
    for (int r = 0; r < 4; ++r) {
      int t = m0 + w * 32 + mf * 16 + grp * 4 + r;
#pragma unroll
      for (int nf = 0; nf < 4; ++nf)
        dst[(size_t)t * 256 + n0 + nf * 16 + i] = acc[mf][nf][r];
    }
}

// ------------------------------------------------------------------
__global__ __launch_bounds__(256) void reduce_kernel(
    const float* __restrict__ Opart, float* __restrict__ out) {
  int gid = blockIdx.x * 256 + threadIdx.x;
  int i4 = gid * 4;
  f32x4 s = *(const f32x4*)&Opart[i4];
#pragma unroll
  for (int z = 1; z < 4; ++z) {
    f32x4 p = *(const f32x4*)&Opart[(size_t)z * (TSEQ * 256) + i4];
    s[0] += p[0]; s[1] += p[1]; s[2] += p[2]; s[3] += p[3];
  }
  *(f32x4*)&out[i4] = s;
}

// ------------------------------------------------------------------
extern "C" void kernel_launch(void* const* d_in, const int* in_sizes, int n_in,
                              void* d_out, int out_size, void* d_ws, size_t ws_size,
                              hipStream_t stream) {
  const float* q  = (const float*)d_in[0];
  const float* k  = (const float*)d_in[1];
  const float* v  = (const float*)d_in[2];
  // d_in[3] = causal mask (always tril) -- applied analytically
  const float* Wq = (const float*)d_in[4];
  const float* Wk = (const float*)d_in[5];
  const float* Wv = (const float*)d_in[6];
  const float* Wo = (const float*)d_in[7];
  float* out = (float*)d_out;

  char* p = (char*)d_ws;
  auto take = [&](size_t nbytes) {
    char* r = p; p += (nbytes + 255) & ~(size_t)255; return r;
  };
  short* qkv  = (short*)take(3ull * TSEQ * 256 * 2);
  short* WqT  = (short*)take(4096ull * 256 * 2);
  short* WkT  = (short*)take(1024ull * 256 * 2);
  short* WvT  = (short*)take(1024ull * 256 * 2);
  short* WoT  = (short*)take(256ull * 4096 * 2);
  float* cosT = (float*)take((size_t)TSEQ * 128 * 4);
  float* sinT = (float*)take((size_t)TSEQ * 128 * 4);
  short* Qr   = (short*)take((size_t)NHQ * TSEQ * DH * 2);
  short* Kr   = (short*)take((size_t)NHK * TSEQ * DH * 2);
  short* Vt   = (short*)take((size_t)NHK * TSEQ * DH * 2);
  short* Oa   = (short*)take((size_t)TSEQ * 4096 * 2);
  // split-K partials alias Qr (dead after attn_kernel; same stream order).
  float* Opart = (float*)Qr;

  hipLaunchKernelGGL(prep_transpose_kernel, dim3(2432), dim3(256), 0, stream,
                     q, k, v, qkv, cosT, sinT,
                     Wq, Wk, Wv, Wo, WqT, WkT, WvT, WoT);
  hipLaunchKernelGGL(proj_kernel, dim3(32, 48), dim3(256), 0, stream,
                     qkv, WqT, WkT, WvT, cosT, sinT, Qr, Kr, Vt);
  hipLaunchKernelGGL(attn_kernel, dim3(16, 32), dim3(512), 0, stream,
                     Qr, Kr, Vt, Oa);
  hipLaunchKernelGGL(outproj_kernel, dim3(16, 4, 4), dim3(256), 0, stream,
                     Oa, WoT, Opart);
  hipLaunchKernelGGL(reduce_kernel, dim3(512), dim3(256), 0, stream,
                     Opart, out);
}

// Round 5
// 228.230 us; speedup vs baseline: 1.5531x; 1.0829x over previous
//
#include <hip/hip_runtime.h>
#include <hip/hip_bf16.h>
#include <math.h>

#define TSEQ 2048
#define NHQ 32
#define NHK 8
#define DH 128

typedef __attribute__((ext_vector_type(8))) short short8;
typedef __attribute__((ext_vector_type(4))) float f32x4;
typedef __attribute__((ext_vector_type(4))) short s16x4;

__device__ __forceinline__ short f2bf(float f) {
  union { float f; unsigned u; } v; v.f = f;
  unsigned r = v.u + 0x7fffu + ((v.u >> 16) & 1u);
  return (short)(r >> 16);
}

__device__ __forceinline__ f32x4 zero4() {
  f32x4 z; z[0] = 0.f; z[1] = 0.f; z[2] = 0.f; z[3] = 0.f; return z;
}

// async 16B global->LDS DMA. LDS dest is wave-uniform base + lane*16 (m104);
// per-lane swizzle goes on the GLOBAL source address (m173).
__device__ __forceinline__ void async_cp16(const short* g, short* l) {
  __builtin_amdgcn_global_load_lds(
      (const __attribute__((address_space(1))) unsigned int*)g,
      (__attribute__((address_space(3))) unsigned int*)l, 16, 0, 0);
}

// ------------------------------------------------------------------
// prep+transpose fused (independent work, one dispatch):
//  blocks [0,1792): q/k/v fp32->bf16 + RoPE cos/sin tables
//  blocks [1792,2432): W fp32 [K][N] -> bf16 [N][K] via 64x64 LDS tiles
// ------------------------------------------------------------------
__global__ __launch_bounds__(256) void prep_transpose_kernel(
    const float* __restrict__ q, const float* __restrict__ k,
    const float* __restrict__ v, short* __restrict__ qkv,
    float* __restrict__ cosT, float* __restrict__ sinT,
    const float* __restrict__ Wq, const float* __restrict__ Wk,
    const float* __restrict__ Wv, const float* __restrict__ Wo,
    short* __restrict__ WqT, short* __restrict__ WkT,
    short* __restrict__ WvT, short* __restrict__ WoT) {
  __shared__ short tl[64][65];
  int bx = blockIdx.x, tid = threadIdx.x;
  if (bx < 1792) {
    int gid = bx * 256 + tid;
    if (gid < 393216) {
      int i4 = gid * 4;
      const float* src = (i4 < 524288) ? (q + i4)
                       : (i4 < 1048576 ? (k + i4 - 524288) : (v + i4 - 1048576));
      float f0 = src[0], f1 = src[1], f2 = src[2], f3 = src[3];
      s16x4 o; o[0] = f2bf(f0); o[1] = f2bf(f1); o[2] = f2bf(f2); o[3] = f2bf(f3);
      *(s16x4*)&qkv[i4] = o;
    } else if (gid < 458752) {
      int idx = (gid - 393216) * 4;
      int t = idx >> 7, d0 = idx & 127;
      float pos = (float)(8192 - TSEQ + t);
#pragma unroll
      for (int jj = 0; jj < 4; ++jj) {
        int d = d0 + jj;
        float inv = exp2f(-0.10381025296522977f * (float)d);
        float f = pos * inv;
        cosT[t * 128 + d] = cosf(f);
        sinT[t * 128 + d] = sinf(f);
      }
    }
    return;
  }
  int b = bx - 1792;
  const float* S; short* D; int K, N, tr, tc;
  if (b < 256)      { S = Wq; D = WqT; K = 256;  N = 4096; tr = b >> 6;        tc = b & 63; }
  else if (b < 320) { S = Wk; D = WkT; K = 256;  N = 1024; int t = b - 256; tr = t >> 4; tc = t & 15; }
  else if (b < 384) { S = Wv; D = WvT; K = 256;  N = 1024; int t = b - 320; tr = t >> 4; tc = t & 15; }
  else              { S = Wo; D = WoT; K = 4096; N = 256;  int t = b - 384; tr = t >> 2; tc = t & 3; }
  int k0 = tr * 64, n0 = tc * 64;
#pragma unroll
  for (int it = 0; it < 4; ++it) {
    int r = it * 16 + (tid >> 4), c = (tid & 15) * 4;
    const float* s = &S[(size_t)(k0 + r) * N + n0 + c];
    tl[r][c + 0] = f2bf(s[0]); tl[r][c + 1] = f2bf(s[1]);
    tl[r][c + 2] = f2bf(s[2]); tl[r][c + 3] = f2bf(s[3]);
  }
  __syncthreads();
#pragma unroll
  for (int it = 0; it < 4; ++it) {
    int rr = it * 16 + (tid >> 4), cc = (tid & 15) * 4;
    s16x4 o;
    o[0] = tl[cc + 0][rr]; o[1] = tl[cc + 1][rr];
    o[2] = tl[cc + 2][rr]; o[3] = tl[cc + 3][rr];
    *(s16x4*)&D[(size_t)(n0 + rr) * K + k0 + cc] = o;
  }
}

// ------------------------------------------------------------------
// proj: X[2048,256] @ W[256,128] per head, RoPE epilogue, bf16 out.
// Q heads additionally pre-scaled by 1/sqrt(DH) (folds softmax scale).
// ------------------------------------------------------------------
#define SCALE 0.08838834764831845f

__global__ __launch_bounds__(256) void proj_kernel(
    const short* __restrict__ qkv,
    const short* __restrict__ WqT, const short* __restrict__ WkT,
    const short* __restrict__ WvT,
    const float* __restrict__ cosT, const float* __restrict__ sinT,
    short* __restrict__ Qr, short* __restrict__ Kr, short* __restrict__ Vt) {
  __shared__ short As[64 * 64];
  __shared__ short Bs[128 * 64];
  int tid = threadIdx.x, lane = tid & 63, w = tid >> 6;
  int i = lane & 15, grp = lane >> 4;
  int bh = blockIdx.y, r0 = blockIdx.x * 64;
  const short* X; const short* Wt; short* dst; int vmode = 0;
  float oscale = 1.0f;
  if (bh < 32)      { X = qkv;                Wt = WqT + bh * (128 * 256);        dst = Qr + (size_t)bh * TSEQ * DH; oscale = SCALE; }
  else if (bh < 40) { X = qkv + TSEQ * 256;   Wt = WkT + (bh - 32) * (128 * 256); dst = Kr + (size_t)(bh - 32) * TSEQ * DH; }
  else              { X = qkv + 2 * TSEQ * 256; Wt = WvT + (bh - 40) * (128 * 256); dst = Vt + (size_t)(bh - 40) * DH * TSEQ; vmode = 1; }

  f32x4 acc[8];
#pragma unroll
  for (int n = 0; n < 8; ++n) acc[n] = zero4();

  for (int kc = 0; kc < 4; ++kc) {
    __syncthreads();
    { // stage A: 64 rows x 64 k (swizzled 16B chunks)
      int row = tid >> 2, p = tid & 3;
      const short* src = X + (size_t)(r0 + row) * 256 + kc * 64 + p * 16;
      short8 d0 = *(const short8*)(src);
      short8 d1 = *(const short8*)(src + 8);
      int c0 = p * 2;
      *(short8*)&As[row * 64 + ((c0 ^ (row & 7)) * 8)] = d0;
      *(short8*)&As[row * 64 + (((c0 + 1) ^ (row & 7)) * 8)] = d1;
    }
    { // stage B: 128 cols x 64 k from transposed weights
      int row = tid >> 1, p = tid & 1;
      const short* src = Wt + (size_t)row * 256 + kc * 64 + p * 32;
#pragma unroll
      for (int jj = 0; jj < 4; ++jj) {
        short8 dv = *(const short8*)(src + jj * 8);
        int c0 = p * 4 + jj;
        *(short8*)&Bs[row * 64 + ((c0 ^ (row & 7)) * 8)] = dv;
      }
    }
    __syncthreads();
#pragma unroll
    for (int kc2 = 0; kc2 < 2; ++kc2) {
      short8 a = *(const short8*)&As[(w * 16 + i) * 64 + (((kc2 * 4 + grp) ^ (i & 7)) * 8)];
#pragma unroll
      for (int n = 0; n < 8; ++n) {
        short8 bf = *(const short8*)&Bs[(n * 16 + i) * 64 + (((kc2 * 4 + grp) ^ (i & 7)) * 8)];
        acc[n] = __builtin_amdgcn_mfma_f32_16x16x32_bf16(a, bf, acc[n], 0, 0, 0);
      }
    }
  }
#pragma unroll
  for (int r = 0; r < 4; ++r) {
    int t = r0 + w * 16 + grp * 4 + r;
    const float* cr = cosT + (size_t)t * 128;
    const float* sr = sinT + (size_t)t * 128;
#pragma unroll
    for (int n = 0; n < 8; ++n) {
      int d = n * 16 + i;
      float x = acc[n][r];
      float xp = acc[n ^ 4][r];
      float rot = (n < 4) ? -xp : xp;
      float val = (x * cr[d] + rot * sr[d]) * oscale;
      short bv = f2bf(val);
      if (vmode) dst[(size_t)d * TSEQ + t] = bv;
      else       dst[(size_t)t * DH + d] = bv;
    }
  }
}

// ------------------------------------------------------------------
// attn: causal flash attention, GQA. QBLK=128 (8 waves x 16 q-rows).
// Paired q-tiles (qt, 15-qt): every block = exactly 34 tile-iters.
// Grid = 256 blocks = 1 block/CU; block id: b&7 = kv-head -> XCD-local K/V.
// K/V double-buffered in LDS via global_load_lds, counted vmcnt(4) +
// raw s_barrier (no drain) -> prefetch overlaps compute. defer-max, setprio.
// ------------------------------------------------------------------
__global__ __launch_bounds__(512, 2) void attn_kernel(
    const short* __restrict__ Qr, const short* __restrict__ Kr,
    const short* __restrict__ Vt, short* __restrict__ Oa) {
  __shared__ __attribute__((aligned(16))) short Ks[2][64 * 128]; // [kv][dh] chunk-swz
  __shared__ __attribute__((aligned(16))) short Vs[2][128 * 64]; // [dh][kv] chunk-swz
  __shared__ short Ps[8][16 * 72];
  int tid = threadIdx.x, lane = tid & 63, w = tid >> 6;  // w in 0..7
  int i = lane & 15, grp = lane >> 4;
  int b = blockIdx.x;
  int hk = b & 7, hq = (b >> 3) & 3, pr = b >> 5;   // b%8 -> XCD heuristic
  int h = hk * 4 + hq;
  const short* Qh = Qr + (size_t)h * TSEQ * DH;
  const short* Kh = Kr + (size_t)hk * TSEQ * DH;
  const short* Vh = Vt + (size_t)hk * DH * TSEQ;

  for (int half = 0; half < 2; ++half) {
    int qt = half ? pr : (15 - pr);       // heavy tile first
    int q0 = qt * 128;
    int qrow = q0 + w * 16 + i;
    short8 qf[4];
#pragma unroll
    for (int c = 0; c < 4; ++c)
      qf[c] = *(const short8*)&Qh[(size_t)qrow * DH + c * 32 + grp * 8];

    f32x4 oacc[8];
#pragma unroll
    for (int n = 0; n < 8; ++n) oacc[n] = zero4();
    float mrow[4], lsum[4];
#pragma unroll
    for (int r = 0; r < 4; ++r) { mrow[r] = -3.0e38f; lsum[r] = 0.0f; }

    int nt = 2 * qt + 2;
    int wave_max_row = q0 + w * 16 + 15;

    // stage(tile, bsel): 4 DMA per wave (2 K halves + 2 V halves)
    auto stage = [&](int kt_, int bsel) {
      int kv0_ = kt_ * 64;
#pragma unroll
      for (int hf = 0; hf < 2; ++hf) {
        int ci = hf * 512 + w * 64 + lane;
        int row = ci >> 4, c = ci & 15;
        async_cp16(Kh + (size_t)(kv0_ + row) * DH + ((c ^ (row & 15)) << 3),
                   &Ks[bsel][hf * 4096 + w * 512]);
      }
#pragma unroll
      for (int hf = 0; hf < 2; ++hf) {
        int ci = hf * 512 + w * 64 + lane;
        int row = ci >> 3, c = ci & 7;
        async_cp16(Vh + (size_t)row * TSEQ + kv0_ + ((c ^ (row & 7)) << 3),
                   &Vs[bsel][hf * 4096 + w * 512]);
      }
    };

    stage(0, 0);
    for (int kt = 0; kt < nt; ++kt) {
      int kv0 = kt * 64;
      int buf = kt & 1;
      if (kt + 1 < nt) {
        stage(kt + 1, buf ^ 1);
        asm volatile("s_waitcnt vmcnt(4)" ::: "memory");  // own tile-kt loads done
      } else {
        asm volatile("s_waitcnt vmcnt(0)" ::: "memory");
      }
      __builtin_amdgcn_s_barrier();   // raw: no vmcnt drain, prefetch stays out
      if (kv0 <= wave_max_row) {      // wave-uniform skip of masked tiles
        const short* Kb = &Ks[buf][0];
        const short* Vb = &Vs[buf][0];
        // S = Q K^T  (rows: q = grp*4+r, cols: kv = n*16+i)
        f32x4 sacc[4];
#pragma unroll
        for (int n = 0; n < 4; ++n) sacc[n] = zero4();
        __builtin_amdgcn_s_setprio(1);
#pragma unroll
        for (int c = 0; c < 4; ++c) {
#pragma unroll
          for (int n = 0; n < 4; ++n) {
            short8 kb = *(const short8*)&Kb[(n * 16 + i) * 128 + (((c * 4 + grp) ^ i) * 8)];
            sacc[n] = __builtin_amdgcn_mfma_f32_16x16x32_bf16(qf[c], kb, sacc[n], 0, 0, 0);
          }
        }
        __builtin_amdgcn_s_setprio(0);
        bool diag = (kt >= nt - 2);   // last two tiles cross the diagonal
        float p_[4][4];
#pragma unroll
        for (int n = 0; n < 4; ++n)
#pragma unroll
          for (int r = 0; r < 4; ++r) {
            float s = sacc[n][r];     // scale pre-folded into Q
            if (diag) {
              int qq = q0 + w * 16 + grp * 4 + r;
              int kk = kv0 + n * 16 + i;
              if (kk > qq) s = -3.0e38f;
            }
            p_[n][r] = s;
          }
        float mnew[4];
#pragma unroll
        for (int r = 0; r < 4; ++r)
          mnew[r] = fmaxf(fmaxf(p_[0][r], p_[1][r]), fmaxf(p_[2][r], p_[3][r]));
#pragma unroll
        for (int off = 1; off <= 8; off <<= 1)
#pragma unroll
          for (int r = 0; r < 4; ++r)
            mnew[r] = fmaxf(mnew[r], __shfl_xor(mnew[r], off));
        // defer-max (T13): skip rescale while max growth <= 8
        bool ok = true;
#pragma unroll
        for (int r = 0; r < 4; ++r) ok = ok && (mnew[r] <= mrow[r] + 8.0f);
        if (!__all(ok ? 1 : 0)) {
#pragma unroll
          for (int r = 0; r < 4; ++r) {
            float mn = fmaxf(mrow[r], mnew[r]);
            float sfv = __expf(mrow[r] - mn);
            mrow[r] = mn;
            lsum[r] *= sfv;
#pragma unroll
            for (int n = 0; n < 8; ++n) oacc[n][r] *= sfv;
          }
        }
#pragma unroll
        for (int n = 0; n < 4; ++n)
#pragma unroll
          for (int r = 0; r < 4; ++r) {
            float p = __expf(p_[n][r] - mrow[r]);
            lsum[r] += p;
            Ps[w][(grp * 4 + r) * 72 + n * 16 + i] = f2bf(p);
          }
        // O += P V
        __builtin_amdgcn_s_setprio(1);
#pragma unroll
        for (int kc = 0; kc < 2; ++kc) {
          short8 pa = *(const short8*)&Ps[w][i * 72 + kc * 32 + grp * 8];
#pragma unroll
          for (int n = 0; n < 8; ++n) {
            short8 vb = *(const short8*)&Vb[(n * 16 + i) * 64 + (((kc * 4 + grp) ^ (i & 7)) * 8)];
            oacc[n] = __builtin_amdgcn_mfma_f32_16x16x32_bf16(pa, vb, oacc[n], 0, 0, 0);
          }
        }
        __builtin_amdgcn_s_setprio(0);
      }
      __builtin_amdgcn_s_barrier();   // buf reusable for stage at next iter
    }
#pragma unroll
    for (int off = 1; off <= 8; off <<= 1)
#pragma unroll
      for (int r = 0; r < 4; ++r) lsum[r] += __shfl_xor(lsum[r], off);
#pragma unroll
    for (int r = 0; r < 4; ++r) {
      int t = q0 + w * 16 + grp * 4 + r;
      float inv = 1.0f / lsum[r];
#pragma unroll
      for (int n = 0; n < 8; ++n) {
        int d = n * 16 + i;
        Oa[(size_t)t * 4096 + h * 128 + d] = f2bf(oacc[n][r] * inv);
      }
    }
  }
}

// ------------------------------------------------------------------
// outproj: Oa[2048,4096] @ Wo[4096,256], split-K=4 -> fp32 partials.
// ------------------------------------------------------------------
__global__ __launch_bounds__(256) void outproj_kernel(
    const short* __restrict__ Oa, const short* __restrict__ WoT,
    float* __restrict__ Opart) {
  __shared__ short As[128 * 64];
  __shared__ short Bs[64 * 64];
  int tid = threadIdx.x, lane = tid & 63, w = tid >> 6;
  int i = lane & 15, grp = lane >> 4;
  int m0 = blockIdx.x * 128, n0 = blockIdx.y * 64, z = blockIdx.z;
  f32x4 acc[2][4];
#pragma unroll
  for (int mf = 0; mf < 2; ++mf)
#pragma unroll
    for (int nf = 0; nf < 4; ++nf) acc[mf][nf] = zero4();
  for (int kc = z * 16; kc < z * 16 + 16; ++kc) {
    __syncthreads();
    {
      int row = tid >> 1, p = tid & 1;
      const short* src = Oa + (size_t)(m0 + row) * 4096 + kc * 64 + p * 32;
#pragma unroll
      for (int jj = 0; jj < 4; ++jj) {
        short8 dv = *(const short8*)(src + jj * 8);
        int c0 = p * 4 + jj;
        *(short8*)&As[row * 64 + ((c0 ^ (row & 7)) * 8)] = dv;
      }
    }
    {
      int row = tid >> 2, p = tid & 3;
      const short* src = WoT + (size_t)(n0 + row) * 4096 + kc * 64 + p * 16;
      short8 d0 = *(const short8*)src;
      short8 d1 = *(const short8*)(src + 8);
      int c0 = p * 2;
      *(short8*)&Bs[row * 64 + ((c0 ^ (row & 7)) * 8)] = d0;
      *(short8*)&Bs[row * 64 + (((c0 + 1) ^ (row & 7)) * 8)] = d1;
    }
    __syncthreads();
#pragma unroll
    for (int kc2 = 0; kc2 < 2; ++kc2) {
#pragma unroll
      for (int mf = 0; mf < 2; ++mf) {
        short8 a = *(const short8*)&As[(w * 32 + mf * 16 + i) * 64 + (((kc2 * 4 + grp) ^ (i & 7)) * 8)];
#pragma unroll
        for (int nf = 0; nf < 4; ++nf) {
          short8 b = *(const short8*)&Bs[(nf * 16 + i) * 64 + (((kc2 * 4 + grp) ^ (i & 7)) * 8)];
          acc[mf][nf] = __builtin_amdgcn_mfma_f32_16x16x32_bf16(a, b, acc[mf][nf], 0, 0, 0);
        }
      }
    }
  }
  float* dst = Opart + (size_t)z * (TSEQ * 256);
#pragma unroll
  for (int mf = 0; mf < 2; ++mf)
#pragma unroll
    for (int r = 0; r < 4; ++r) {
      int t = m0 + w * 32 + mf * 16 + grp * 4 + r;
#pragma unroll
      for (int nf = 0; nf < 4; ++nf)
        dst[(size_t)t * 256 + n0 + nf * 16 + i] = acc[mf][nf][r];
    }
}

// ------------------------------------------------------------------
__global__ __launch_bounds__(256) void reduce_kernel(
    const float* __restrict__ Opart, float* __restrict__ out) {
  int gid = blockIdx.x * 256 + threadIdx.x;
  int i4 = gid * 4;
  f32x4 s = *(const f32x4*)&Opart[i4];
#pragma unroll
  for (int z = 1; z < 4; ++z) {
    f32x4 p = *(const f32x4*)&Opart[(size_t)z * (TSEQ * 256) + i4];
    s[0] += p[0]; s[1] += p[1]; s[2] += p[2]; s[3] += p[3];
  }
  *(f32x4*)&out[i4] = s;
}

// ------------------------------------------------------------------
extern "C" void kernel_launch(void* const* d_in, const int* in_sizes, int n_in,
                              void* d_out, int out_size, void* d_ws, size_t ws_size,
                              hipStream_t stream) {
  const float* q  = (const float*)d_in[0];
  const float* k  = (const float*)d_in[1];
  const float* v  = (const float*)d_in[2];
  // d_in[3] = causal mask (always tril) -- applied analytically
  const float* Wq = (const float*)d_in[4];
  const float* Wk = (const float*)d_in[5];
  const float* Wv = (const float*)d_in[6];
  const float* Wo = (const float*)d_in[7];
  float* out = (float*)d_out;

  char* p = (char*)d_ws;
  auto take = [&](size_t nbytes) {
    char* r = p; p += (nbytes + 255) & ~(size_t)255; return r;
  };
  short* qkv  = (short*)take(3ull * TSEQ * 256 * 2);
  short* WqT  = (short*)take(4096ull * 256 * 2);
  short* WkT  = (short*)take(1024ull * 256 * 2);
  short* WvT  = (short*)take(1024ull * 256 * 2);
  short* WoT  = (short*)take(256ull * 4096 * 2);
  float* cosT = (float*)take((size_t)TSEQ * 128 * 4);
  float* sinT = (float*)take((size_t)TSEQ * 128 * 4);
  short* Qr   = (short*)take((size_t)NHQ * TSEQ * DH * 2);
  short* Kr   = (short*)take((size_t)NHK * TSEQ * DH * 2);
  short* Vt   = (short*)take((size_t)NHK * TSEQ * DH * 2);
  short* Oa   = (short*)take((size_t)TSEQ * 4096 * 2);
  // split-K partials alias Qr (dead after attn_kernel; same stream order).
  float* Opart = (float*)Qr;

  hipLaunchKernelGGL(prep_transpose_kernel, dim3(2432), dim3(256), 0, stream,
                     q, k, v, qkv, cosT, sinT,
                     Wq, Wk, Wv, Wo, WqT, WkT, WvT, WoT);
  hipLaunchKernelGGL(proj_kernel, dim3(32, 48), dim3(256), 0, stream,
                     qkv, WqT, WkT, WvT, cosT, sinT, Qr, Kr, Vt);
  hipLaunchKernelGGL(attn_kernel, dim3(256), dim3(512), 0, stream,
                     Qr, Kr, Vt, Oa);
  hipLaunchKernelGGL(outproj_kernel, dim3(16, 4, 4), dim3(256), 0, stream,
                     Oa, WoT, Opart);
  hipLaunchKernelGGL(reduce_kernel, dim3(512), dim3(256), 0, stream,
                     Opart, out);
}

// Round 7
// 200.274 us; speedup vs baseline: 1.7699x; 1.1396x over previous
//
#include <hip/hip_runtime.h>
#include <hip/hip_bf16.h>
#include <math.h>

#define TSEQ 2048
#define NHQ 32
#define NHK 8
#define DH 128

typedef __attribute__((ext_vector_type(8))) short short8;
typedef __attribute__((ext_vector_type(4))) float f32x4;
typedef __attribute__((ext_vector_type(4))) short s16x4;

__device__ __forceinline__ short f2bf(float f) {
  union { float f; unsigned u; } v; v.f = f;
  unsigned r = v.u + 0x7fffu + ((v.u >> 16) & 1u);
  return (short)(r >> 16);
}

__device__ __forceinline__ f32x4 zero4() {
  f32x4 z; z[0] = 0.f; z[1] = 0.f; z[2] = 0.f; z[3] = 0.f; return z;
}

// async 16B global->LDS DMA. LDS dest is wave-uniform base + lane*16 (m104);
// per-lane swizzle goes on the GLOBAL source address (m173).
__device__ __forceinline__ void async_cp16(const short* g, short* l) {
  __builtin_amdgcn_global_load_lds(
      (const __attribute__((address_space(1))) unsigned int*)g,
      (__attribute__((address_space(3))) unsigned int*)l, 16, 0, 0);
}

// ------------------------------------------------------------------
// prep+transpose fused (independent work, one dispatch)
// ------------------------------------------------------------------
__global__ __launch_bounds__(256) void prep_transpose_kernel(
    const float* __restrict__ q, const float* __restrict__ k,
    const float* __restrict__ v, short* __restrict__ qkv,
    float* __restrict__ cosT, float* __restrict__ sinT,
    const float* __restrict__ Wq, const float* __restrict__ Wk,
    const float* __restrict__ Wv, const float* __restrict__ Wo,
    short* __restrict__ WqT, short* __restrict__ WkT,
    short* __restrict__ WvT, short* __restrict__ WoT) {
  __shared__ short tl[64][65];
  int bx = blockIdx.x, tid = threadIdx.x;
  if (bx < 1792) {
    int gid = bx * 256 + tid;
    if (gid < 393216) {
      int i4 = gid * 4;
      const float* src = (i4 < 524288) ? (q + i4)
                       : (i4 < 1048576 ? (k + i4 - 524288) : (v + i4 - 1048576));
      float f0 = src[0], f1 = src[1], f2 = src[2], f3 = src[3];
      s16x4 o; o[0] = f2bf(f0); o[1] = f2bf(f1); o[2] = f2bf(f2); o[3] = f2bf(f3);
      *(s16x4*)&qkv[i4] = o;
    } else if (gid < 458752) {
      int idx = (gid - 393216) * 4;
      int t = idx >> 7, d0 = idx & 127;
      float pos = (float)(8192 - TSEQ + t);
#pragma unroll
      for (int jj = 0; jj < 4; ++jj) {
        int d = d0 + jj;
        float inv = exp2f(-0.10381025296522977f * (float)d);
        float f = pos * inv;
        cosT[t * 128 + d] = cosf(f);
        sinT[t * 128 + d] = sinf(f);
      }
    }
    return;
  }
  int b = bx - 1792;
  const float* S; short* D; int K, N, tr, tc;
  if (b < 256)      { S = Wq; D = WqT; K = 256;  N = 4096; tr = b >> 6;        tc = b & 63; }
  else if (b < 320) { S = Wk; D = WkT; K = 256;  N = 1024; int t = b - 256; tr = t >> 4; tc = t & 15; }
  else if (b < 384) { S = Wv; D = WvT; K = 256;  N = 1024; int t = b - 320; tr = t >> 4; tc = t & 15; }
  else              { S = Wo; D = WoT; K = 4096; N = 256;  int t = b - 384; tr = t >> 2; tc = t & 3; }
  int k0 = tr * 64, n0 = tc * 64;
#pragma unroll
  for (int it = 0; it < 4; ++it) {
    int r = it * 16 + (tid >> 4), c = (tid & 15) * 4;
    const float* s = &S[(size_t)(k0 + r) * N + n0 + c];
    tl[r][c + 0] = f2bf(s[0]); tl[r][c + 1] = f2bf(s[1]);
    tl[r][c + 2] = f2bf(s[2]); tl[r][c + 3] = f2bf(s[3]);
  }
  __syncthreads();
#pragma unroll
  for (int it = 0; it < 4; ++it) {
    int rr = it * 16 + (tid >> 4), cc = (tid & 15) * 4;
    s16x4 o;
    o[0] = tl[cc + 0][rr]; o[1] = tl[cc + 1][rr];
    o[2] = tl[cc + 2][rr]; o[3] = tl[cc + 3][rr];
    *(s16x4*)&D[(size_t)(n0 + rr) * K + k0 + cc] = o;
  }
}

// ------------------------------------------------------------------
// proj: X[2048,256] @ W[256,128] per head, RoPE epilogue, bf16 out.
// DMA-staged (pre-swizzled source), double-buffered, counted vmcnt.
// Q pre-scaled by 1/sqrt(DH).
// ------------------------------------------------------------------
#define SCALE 0.08838834764831845f

__global__ __launch_bounds__(256) void proj_kernel(
    const short* __restrict__ qkv,
    const short* __restrict__ WqT, const short* __restrict__ WkT,
    const short* __restrict__ WvT,
    const float* __restrict__ cosT, const float* __restrict__ sinT,
    short* __restrict__ Qr, short* __restrict__ Kr, short* __restrict__ Vt) {
  __shared__ __attribute__((aligned(16))) short As[2][64 * 64];
  __shared__ __attribute__((aligned(16))) short Bs[2][128 * 64];
  int tid = threadIdx.x, lane = tid & 63, w = tid >> 6;
  int i = lane & 15, grp = lane >> 4;
  int bh = blockIdx.y, r0 = blockIdx.x * 64;
  const short* X; const short* Wt; short* dst; int vmode = 0;
  float oscale = 1.0f;
  if (bh < 32)      { X = qkv;                Wt = WqT + bh * (128 * 256);        dst = Qr + (size_t)bh * TSEQ * DH; oscale = SCALE; }
  else if (bh < 40) { X = qkv + TSEQ * 256;   Wt = WkT + (bh - 32) * (128 * 256); dst = Kr + (size_t)(bh - 32) * TSEQ * DH; }
  else              { X = qkv + 2 * TSEQ * 256; Wt = WvT + (bh - 40) * (128 * 256); dst = Vt + (size_t)(bh - 40) * DH * TSEQ; vmode = 1; }

  // per-lane DMA sources (chunk = 8 shorts; LDS linear, src pre-swizzled)
  const short* srcA[2];
#pragma unroll
  for (int j = 0; j < 2; ++j) {
    int ci = w * 128 + j * 64 + lane;
    int row = ci >> 3, c = ci & 7;
    srcA[j] = X + (size_t)(r0 + row) * 256 + ((c ^ (row & 7)) << 3);
  }
  const short* srcB[4];
#pragma unroll
  for (int j = 0; j < 4; ++j) {
    int ci = w * 256 + j * 64 + lane;
    int row = ci >> 3, c = ci & 7;
    srcB[j] = Wt + (size_t)row * 256 + ((c ^ (row & 7)) << 3);
  }
  auto stage = [&](int kc_, int bsel) {
#pragma unroll
    for (int j = 0; j < 2; ++j)
      async_cp16(srcA[j] + kc_ * 64, &As[bsel][(w * 128 + j * 64) * 8]);
#pragma unroll
    for (int j = 0; j < 4; ++j)
      async_cp16(srcB[j] + kc_ * 64, &Bs[bsel][(w * 256 + j * 64) * 8]);
  };

  f32x4 acc[8];
#pragma unroll
  for (int n = 0; n < 8; ++n) acc[n] = zero4();

  stage(0, 0);
  for (int kc = 0; kc < 4; ++kc) {
    int buf = kc & 1;
    if (kc < 3) {
      stage(kc + 1, buf ^ 1);
      asm volatile("s_waitcnt vmcnt(6)" ::: "memory");
    } else {
      asm volatile("s_waitcnt vmcnt(0)" ::: "memory");
    }
    __builtin_amdgcn_s_barrier();
#pragma unroll
    for (int kc2 = 0; kc2 < 2; ++kc2) {
      short8 a = *(const short8*)&As[buf][(w * 16 + i) * 64 + (((kc2 * 4 + grp) ^ (i & 7)) * 8)];
#pragma unroll
      for (int n = 0; n < 8; ++n) {
        short8 bf = *(const short8*)&Bs[buf][(n * 16 + i) * 64 + (((kc2 * 4 + grp) ^ (i & 7)) * 8)];
        acc[n] = __builtin_amdgcn_mfma_f32_16x16x32_bf16(a, bf, acc[n], 0, 0, 0);
      }
    }
    __builtin_amdgcn_s_barrier();
  }
#pragma unroll
  for (int r = 0; r < 4; ++r) {
    int t = r0 + w * 16 + grp * 4 + r;
    const float* cr = cosT + (size_t)t * 128;
    const float* sr = sinT + (size_t)t * 128;
#pragma unroll
    for (int n = 0; n < 8; ++n) {
      int d = n * 16 + i;
      float x = acc[n][r];
      float xp = acc[n ^ 4][r];
      float rot = (n < 4) ? -xp : xp;
      float val = (x * cr[d] + rot * sr[d]) * oscale;
      short bv = f2bf(val);
      if (vmode) dst[(size_t)d * TSEQ + t] = bv;
      else       dst[(size_t)t * DH + d] = bv;
    }
  }
}

// ------------------------------------------------------------------
// attn: causal flash attention, GQA. QBLK=128 (8 waves x 16 q-rows).
// SWAPPED QK^T (S^T = mfma(K,Q)): lane owns 16 kv of ONE q-row ->
// lane-local softmax (2 shfl), packed b64 P-stores. Paired q-tiles,
// b&7 XCD map, dbuf DMA staging w/ vmcnt(4), defer-max, setprio.
// ------------------------------------------------------------------
__global__ __launch_bounds__(512, 2) void attn_kernel(
    const short* __restrict__ Qr, const short* __restrict__ Kr,
    const short* __restrict__ Vt, short* __restrict__ Oa) {
  __shared__ __attribute__((aligned(16))) short Ks[2][64 * 128]; // [kv][dh] chunk-swz
  __shared__ __attribute__((aligned(16))) short Vs[2][128 * 64]; // [dh][kv] chunk-swz
  __shared__ __attribute__((aligned(16))) short Ps[8][16 * 72];  // [q][kv], stride 72
  int tid = threadIdx.x, lane = tid & 63, w = tid >> 6;  // w in 0..7
  int i = lane & 15, grp = lane >> 4;
  int b = blockIdx.x;
  int hk = b & 7, hq = (b >> 3) & 3, pr = b >> 5;   // b%8 -> XCD heuristic
  int h = hk * 4 + hq;
  const short* Qh = Qr + (size_t)h * TSEQ * DH;
  const short* Kh = Kr + (size_t)hk * TSEQ * DH;
  const short* Vh = Vt + (size_t)hk * DH * TSEQ;

  // hoisted per-lane DMA source bases (advance by kv0 per tile)
  const short* kst[2]; const short* vst[2];
#pragma unroll
  for (int hf = 0; hf < 2; ++hf) {
    int ci = hf * 512 + w * 64 + lane;
    int rk = ci >> 4, ck = ci & 15;
    kst[hf] = Kh + (size_t)rk * DH + ((ck ^ (rk & 15)) << 3);
    int rv = ci >> 3, cv = ci & 7;
    vst[hf] = Vh + (size_t)rv * TSEQ + ((cv ^ (rv & 7)) << 3);
  }

  for (int half = 0; half < 2; ++half) {
    int qt = half ? pr : (15 - pr);       // heavy tile first
    int q0 = qt * 128;
    int qq = q0 + w * 16 + i;             // this lane's q-row (swapped layout)
    short8 qf[4];
#pragma unroll
    for (int c = 0; c < 4; ++c)
      qf[c] = *(const short8*)&Qh[(size_t)qq * DH + c * 32 + grp * 8];

    f32x4 oacc[8];
#pragma unroll
    for (int n = 0; n < 8; ++n) oacc[n] = zero4();
    float mrow = -3.0e38f, lsum = 0.0f;   // lane-local (q = i), lsum partial

    int nt = 2 * qt + 2;
    int wave_max_row = q0 + w * 16 + 15;

    auto stage = [&](int kt_, int bsel) {
      int kv0_ = kt_ * 64;
      async_cp16(kst[0] + (size_t)kv0_ * DH, &Ks[bsel][w * 512]);
      async_cp16(kst[1] + (size_t)kv0_ * DH, &Ks[bsel][4096 + w * 512]);
      async_cp16(vst[0] + kv0_, &Vs[bsel][w * 512]);
      async_cp16(vst[1] + kv0_, &Vs[bsel][4096 + w * 512]);
    };

    stage(0, 0);
    for (int kt = 0; kt < nt; ++kt) {
      int kv0 = kt * 64;
      int buf = kt & 1;
      if (kt + 1 < nt) {
        stage(kt + 1, buf ^ 1);
        asm volatile("s_waitcnt vmcnt(4)" ::: "memory");
      } else {
        asm volatile("s_waitcnt vmcnt(0)" ::: "memory");
      }
      __builtin_amdgcn_s_barrier();
      if (kv0 <= wave_max_row) {
        const short* Kb = &Ks[buf][0];
        const short* Vb = &Vs[buf][0];
        // S^T = K Q^T: D[row=kv=n*16+grp*4+r][col=q=i]
        f32x4 sacc[4];
#pragma unroll
        for (int n = 0; n < 4; ++n) sacc[n] = zero4();
        __builtin_amdgcn_s_setprio(1);
#pragma unroll
        for (int c = 0; c < 4; ++c) {
#pragma unroll
          for (int n = 0; n < 4; ++n) {
            short8 kb = *(const short8*)&Kb[(n * 16 + i) * 128 + (((c * 4 + grp) ^ i) * 8)];
            sacc[n] = __builtin_amdgcn_mfma_f32_16x16x32_bf16(kb, qf[c], sacc[n], 0, 0, 0);
          }
        }
        __builtin_amdgcn_s_setprio(0);
        bool diag = (kt >= nt - 2);
        float p_[4][4];
#pragma unroll
        for (int n = 0; n < 4; ++n)
#pragma unroll
          for (int r = 0; r < 4; ++r) {
            float s = sacc[n][r];
            if (diag) {
              int kk = kv0 + n * 16 + grp * 4 + r;
              if (kk > qq) s = -3.0e38f;
            }
            p_[n][r] = s;
          }
        // lane-local max over 16 kv + 2 shfl across grp lanes (same q)
        float mnew = p_[0][0];
#pragma unroll
        for (int n = 0; n < 4; ++n)
#pragma unroll
          for (int r = 0; r < 4; ++r) mnew = fmaxf(mnew, p_[n][r]);
        mnew = fmaxf(mnew, __shfl_xor(mnew, 16));
        mnew = fmaxf(mnew, __shfl_xor(mnew, 32));
        // defer-max (T13)
        if (__any((mnew > mrow + 8.0f) ? 1 : 0)) {
          float mn = fmaxf(mrow, mnew);
          float sfv = __expf(mrow - mn);
          mrow = mn;
          lsum *= sfv;
          float sf0 = __shfl(sfv, grp * 4 + 0);
          float sf1 = __shfl(sfv, grp * 4 + 1);
          float sf2 = __shfl(sfv, grp * 4 + 2);
          float sf3 = __shfl(sfv, grp * 4 + 3);
#pragma unroll
          for (int n = 0; n < 8; ++n) {
            oacc[n][0] *= sf0; oacc[n][1] *= sf1;
            oacc[n][2] *= sf2; oacc[n][3] *= sf3;
          }
        }
        // P = exp(s - m): pack 4 consecutive kv -> one b64 store
#pragma unroll
        for (int n = 0; n < 4; ++n) {
          float e0 = __expf(p_[n][0] - mrow);
          float e1 = __expf(p_[n][1] - mrow);
          float e2 = __expf(p_[n][2] - mrow);
          float e3 = __expf(p_[n][3] - mrow);
          lsum += (e0 + e1) + (e2 + e3);
          unsigned lo, hi;
          asm("v_cvt_pk_bf16_f32 %0, %1, %2" : "=v"(lo) : "v"(e0), "v"(e1));
          asm("v_cvt_pk_bf16_f32 %0, %1, %2" : "=v"(hi) : "v"(e2), "v"(e3));
          *(unsigned long long*)&Ps[w][i * 72 + n * 16 + grp * 4] =
              ((unsigned long long)hi << 32) | lo;
        }
        // O += P V  (A = P[q][kv], B = V^T)
        __builtin_amdgcn_s_setprio(1);
#pragma unroll
        for (int kc = 0; kc < 2; ++kc) {
          short8 pa = *(const short8*)&Ps[w][i * 72 + kc * 32 + grp * 8];
#pragma unroll
          for (int n = 0; n < 8; ++n) {
            short8 vb = *(const short8*)&Vb[(n * 16 + i) * 64 + (((kc * 4 + grp) ^ (i & 7)) * 8)];
            oacc[n] = __builtin_amdgcn_mfma_f32_16x16x32_bf16(pa, vb, oacc[n], 0, 0, 0);
          }
        }
        __builtin_amdgcn_s_setprio(0);
      }
      __builtin_amdgcn_s_barrier();
    }
    // final lsum reduce across grp lanes, then per-row normalize
    lsum += __shfl_xor(lsum, 16);
    lsum += __shfl_xor(lsum, 32);
    float inv[4];
#pragma unroll
    for (int r = 0; r < 4; ++r) inv[r] = 1.0f / __shfl(lsum, grp * 4 + r);
#pragma unroll
    for (int r = 0; r < 4; ++r) {
      int t = q0 + w * 16 + grp * 4 + r;
#pragma unroll
      for (int n = 0; n < 8; ++n) {
        int d = n * 16 + i;
        Oa[(size_t)t * 4096 + h * 128 + d] = f2bf(oacc[n][r] * inv[r]);
      }
    }
  }
}

// ------------------------------------------------------------------
// outproj: Oa[2048,4096] @ Wo[4096,256], split-K=4 -> fp32 partials.
// DMA-staged, double-buffered, counted vmcnt.
// ------------------------------------------------------------------
__global__ __launch_bounds__(256) void outproj_kernel(
    const short* __restrict__ Oa, const short* __restrict__ WoT,
    float* __restrict__ Opart) {
  __shared__ __attribute__((aligned(16))) short As[2][128 * 64];
  __shared__ __attribute__((aligned(16))) short Bs[2][64 * 64];
  int tid = threadIdx.x, lane = tid & 63, w = tid >> 6;
  int i = lane & 15, grp = lane >> 4;
  int m0 = blockIdx.x * 128, n0 = blockIdx.y * 64, z = blockIdx.z;

  const short* srcA[4];
#pragma unroll
  for (int j = 0; j < 4; ++j) {
    int ci = w * 256 + j * 64 + lane;
    int row = ci >> 3, c = ci & 7;
    srcA[j] = Oa + (size_t)(m0 + row) * 4096 + (size_t)z * 1024 + ((c ^ (row & 7)) << 3);
  }
  const short* srcB[2];
#pragma unroll
  for (int j = 0; j < 2; ++j) {
    int ci = w * 128 + j * 64 + lane;
    int row = ci >> 3, c = ci & 7;
    srcB[j] = WoT + (size_t)(n0 + row) * 4096 + (size_t)z * 1024 + ((c ^ (row & 7)) << 3);
  }
  auto stage = [&](int kc_, int bsel) {
#pragma unroll
    for (int j = 0; j < 4; ++j)
      async_cp16(srcA[j] + kc_ * 64, &As[bsel][(w * 256 + j * 64) * 8]);
#pragma unroll
    for (int j = 0; j < 2; ++j)
      async_cp16(srcB[j] + kc_ * 64, &Bs[bsel][(w * 128 + j * 64) * 8]);
  };

  f32x4 acc[2][4];
#pragma unroll
  for (int mf = 0; mf < 2; ++mf)
#pragma unroll
    for (int nf = 0; nf < 4; ++nf) acc[mf][nf] = zero4();

  stage(0, 0);
  for (int kc = 0; kc < 16; ++kc) {
    int buf = kc & 1;
    if (kc < 15) {
      stage(kc + 1, buf ^ 1);
      asm volatile("s_waitcnt vmcnt(6)" ::: "memory");
    } else {
      asm volatile("s_waitcnt vmcnt(0)" ::: "memory");
    }
    __builtin_amdgcn_s_barrier();
#pragma unroll
    for (int kc2 = 0; kc2 < 2; ++kc2) {
#pragma unroll
      for (int mf = 0; mf < 2; ++mf) {
        short8 a = *(const short8*)&As[buf][(w * 32 + mf * 16 + i) * 64 + (((kc2 * 4 + grp) ^ (i & 7)) * 8)];
#pragma unroll
        for (int nf = 0; nf < 4; ++nf) {
          short8 bb = *(const short8*)&Bs[buf][(nf * 16 + i) * 64 + (((kc2 * 4 + grp) ^ (i & 7)) * 8)];
          acc[mf][nf] = __builtin_amdgcn_mfma_f32_16x16x32_bf16(a, bb, acc[mf][nf], 0, 0, 0);
        }
      }
    }
    __builtin_amdgcn_s_barrier();
  }
  float* dst = Opart + (size_t)z * (TSEQ * 256);
#pragma unroll
  for (int mf = 0; mf < 2; ++mf)
#pragma unroll
    for (int r = 0; r < 4; ++r) {
      int t = m0 + w * 32 + mf * 16 + grp * 4 + r;
#pragma unroll
      for (int nf = 0; nf < 4; ++nf)
        dst[(size_t)t * 256 + n0 + nf * 16 + i] = acc[mf][nf][r];
    }
}

// ------------------------------------------------------------------
__global__ __launch_bounds__(256) void reduce_kernel(
    const float* __restrict__ Opart, float* __restrict__ out) {
  int gid = blockIdx.x * 256 + threadIdx.x;
  int i4 = gid * 4;
  f32x4 s = *(const f32x4*)&Opart[i4];
#pragma unroll
  for (int z = 1; z < 4; ++z) {
    f32x4 p = *(const f32x4*)&Opart[(size_t)z * (TSEQ * 256) + i4];
    s[0] += p[0]; s[1] += p[1]; s[2] += p[2]; s[3] += p[3];
  }
  *(f32x4*)&out[i4] = s;
}

// ------------------------------------------------------------------
extern "C" void kernel_launch(void* const* d_in, const int* in_sizes, int n_in,
                              void* d_out, int out_size, void* d_ws, size_t ws_size,
                              hipStream_t stream) {
  const float* q  = (const float*)d_in[0];
  const float* k  = (const float*)d_in[1];
  const float* v  = (const float*)d_in[2];
  // d_in[3] = causal mask (always tril) -- applied analytically
  const float* Wq = (const float*)d_in[4];
  const float* Wk = (const float*)d_in[5];
  const float* Wv = (const float*)d_in[6];
  const float* Wo = (const float*)d_in[7];
  float* out = (float*)d_out;

  char* p = (char*)d_ws;
  auto take = [&](size_t nbytes) {
    char* r = p; p += (nbytes + 255) & ~(size_t)255; return r;
  };
  short* qkv  = (short*)take(3ull * TSEQ * 256 * 2);
  short* WqT  = (short*)take(4096ull * 256 * 2);
  short* WkT  = (short*)take(1024ull * 256 * 2);
  short* WvT  = (short*)take(1024ull * 256 * 2);
  short* WoT  = (short*)take(256ull * 4096 * 2);
  float* cosT = (float*)take((size_t)TSEQ * 128 * 4);
  float* sinT = (float*)take((size_t)TSEQ * 128 * 4);
  short* Qr   = (short*)take((size_t)NHQ * TSEQ * DH * 2);
  short* Kr   = (short*)take((size_t)NHK * TSEQ * DH * 2);
  short* Vt   = (short*)take((size_t)NHK * TSEQ * DH * 2);
  short* Oa   = (short*)take((size_t)TSEQ * 4096 * 2);
  // split-K partials alias Qr (dead after attn_kernel; same stream order).
  float* Opart = (float*)Qr;

  hipLaunchKernelGGL(prep_transpose_kernel, dim3(2432), dim3(256), 0, stream,
                     q, k, v, qkv, cosT, sinT,
                     Wq, Wk, Wv, Wo, WqT, WkT, WvT, WoT);
  hipLaunchKernelGGL(proj_kernel, dim3(32, 48), dim3(256), 0, stream,
                     qkv, WqT, WkT, WvT, cosT, sinT, Qr, Kr, Vt);
  hipLaunchKernelGGL(attn_kernel, dim3(256), dim3(512), 0, stream,
                     Qr, Kr, Vt, Oa);
  hipLaunchKernelGGL(outproj_kernel, dim3(16, 4, 4), dim3(256), 0, stream,
                     Oa, WoT, Opart);
  hipLaunchKernelGGL(reduce_kernel, dim3(512), dim3(256), 0, stream,
                     Opart, out);
}